// Round 10
// baseline (1905.094 us; speedup 1.0000x reference)
//
#include <hip/hip_runtime.h>
#include <math.h>

// CV-photonic circuit: WIRES=4, LAYERS=2, CUTOFF=10, BATCH=2048.
// R10 = R9 + pre-shaped gate tables: real tables stored as splat v2f (w,w),
// complex tables as float4 (ux,ux,-uy,uy). Gate bodies now do ZERO operand
// construction: real (i,k) = 1 dwordx2 + 1 v_pk_fma_f32; complex (i,k) =
// 1 dwordx4 + 2 v_pk_fma_f32. Still no local arrays (named v2f accumulators).

namespace {

constexpr int NTB = 1024;                // threads per state block (16 waves)
constexpr int SMEM_BYTES = 80384;        // state 80000 + uv 320 + red 64
constexpr double THETA = 0.7853981633974483096; // pi/4

struct cxf { float x, y; };
struct cxd { double x, y; };
typedef float v2f __attribute__((ext_vector_type(2)));
typedef float v4f __attribute__((ext_vector_type(4)));

// ws float layout (16B-aligned sections):
// [0,200)        Vp   splat pairs of V[k*10+m]        (V^T gate)
// [256,456)      VTp  splat pairs of VT[k*10+i]=V[i][k] (V gate)
// [512,2512)     Wp   10 mats x 100 x (w,w)           (transposed per n)
// [2560,10160)   BS4  19 x 100 x (ux,ux,-uy,uy)       (transposed, zero-pad)
// [10240,13440)  UL4  8 x 100 x (ux,ux,-uy,uy)        (transposed)
// [13568,...)    u    cxf[B*4*10] encoded per-(b,w) vectors

__device__ __forceinline__ cxd gen_squeeze(int i, int j, double zr, double zi){
  if (j == i+2){ double g = 0.5*sqrt((double)((i+1)*(i+2))); return {zr*g, -zi*g}; }
  if (i == j+2){ double g = 0.5*sqrt((double)((j+1)*(j+2))); return {-zr*g, -zi*g}; }
  return {0.0, 0.0};
}
__device__ __forceinline__ cxd gen_disp(int i, int j, double ar, double ai){
  if (i == j+1){ double g = sqrt((double)i); return {ar*g, ai*g}; }
  if (j == i+1){ double g = sqrt((double)j); return {-ar*g, ai*g}; }
  return {0.0, 0.0};
}

// Wave-cooperative fixed-schedule expm: result = exp(M), n x n (n<=10).
__device__ void expm_fixed(bool act, int n, cxd* M, cxd* P, cxd* T, cxd* R, int lane){
  const int n2 = n*n;
  if (act){
    for (int e=lane; e<n2; e+=64){ M[e].x *= 0x1p-10; M[e].y *= 0x1p-10; }
    for (int e=lane; e<n2; e+=64){
      P[e] = M[e];
      cxd r = M[e];
      if (e % (n+1) == 0) r.x += 1.0;
      R[e] = r;
    }
  }
  __syncthreads();
  for (int t=2; t<=12; ++t){
    if (act){
      double inv = 1.0/(double)t;
      for (int e=lane; e<n2; e+=64){
        int i = e/n, j = e - i*n;
        double ax=0.0, ay=0.0;
        for (int k=0;k<n;k++){
          cxd p = P[i*n+k], m = M[k*n+j];
          ax += p.x*m.x - p.y*m.y;
          ay += p.x*m.y + p.y*m.x;
        }
        T[e] = {ax*inv, ay*inv};
      }
    }
    __syncthreads();
    { cxd* tmp = P; P = T; T = tmp; }
    if (act){ for (int e=lane; e<n2; e+=64){ R[e].x += P[e].x; R[e].y += P[e].y; } }
    __syncthreads();
  }
  for (int s=0; s<10; ++s){
    if (act){
      for (int e=lane; e<n2; e+=64){
        int i = e/n, j = e - i*n;
        double ax=0.0, ay=0.0;
        for (int k=0;k<n;k++){
          cxd p = R[i*n+k], q = R[k*n+j];
          ax += p.x*q.x - p.y*q.y;
          ay += p.x*q.y + p.y*q.x;
        }
        T[e] = {ax, ay};
      }
    }
    __syncthreads();
    { cxd* tmp = R; R = T; T = tmp; }
    __syncthreads();
  }
}

// ------------- Kernel A: shared gate tables into d_ws (8 blocks) -----------
__global__ __launch_bounds__(256)
void gates_kernel(const float* __restrict__ dmag, const float* __restrict__ dphase,
                  const float* __restrict__ smag, const float* __restrict__ sphase,
                  float* __restrict__ wsf){
  __shared__ double lam[10];
  __shared__ double Vd[100];
  __shared__ double scr[4][4][200];     // [wave][buf] cxd[100]
  __shared__ double layres[16][200];    // S_lay (0..7), D_lay (8..15)
  const int tid = threadIdx.x;
  const int wv = tid >> 6, lane = tid & 63, g = blockIdx.x;
  float* ws_Vp  = wsf;
  float* ws_VTp = wsf + 256;
  float* ws_Wp  = wsf + 512;
  float* ws_BS4 = wsf + 2560;
  float* ws_UL4 = wsf + 10240;

  if (tid < 10){
    double lo = -6.0, hi = 6.0;
    for (int it=0; it<80; ++it){
      double mid = 0.5*(lo+hi);
      int cnt = 0; double q = 1.0;
      for (int i=0;i<10;i++){
        q = -mid - (i ? (double)i/q : 0.0);
        if (fabs(q) < 1e-300) q = -1e-300;
        if (q < 0.0) cnt++;
      }
      if (cnt > tid) hi = mid; else lo = mid;
    }
    double x = 0.5*(lo+hi);
    double p[10];
    p[0] = 1.0; p[1] = x;
    for (int k=1;k<9;k++) p[k+1] = (x*p[k] - sqrt((double)k)*p[k-1]) * (1.0/sqrt((double)(k+1)));
    double nn=0.0; for (int k=0;k<10;k++) nn += p[k]*p[k];
    double inv = 1.0/sqrt(nn);
    lam[tid] = x;
    for (int k=0;k<10;k++){
      Vd[k*10+tid] = p[k]*inv;
      if (g == 0){
        float v = (float)(p[k]*inv);
        ws_Vp [(k*10+tid)*2+0] = v;  ws_Vp [(k*10+tid)*2+1] = v;   // V[k][m] splat
        ws_VTp[(tid*10+k)*2+0] = v;  ws_VTp[(tid*10+k)*2+1] = v;   // VT[m][k] splat
      }
    }
  }
  __syncthreads();

  const int nrounds = (g==7) ? 5 : 1;
  for (int r=0; r<nrounds; ++r){
    int t;
    if (g < 7) t = 4*g + wv;
    else       t = (r==0) ? ((wv==0) ? 28 : 64) : (29 + (r-1)*4 + wv);
    bool act = (t < 45);
    int n = 10, bn = 0, ilo = 0;
    if (act && t >= 10 && t < 29){
      bn = t - 10; ilo = bn < 10 ? 0 : bn - 9;
      int ihi = bn < 10 ? bn : 9;
      n = ihi - ilo + 1;
    }
    cxd* M = (cxd*)scr[wv][0];
    cxd* P = (cxd*)scr[wv][1];
    cxd* T = (cxd*)scr[wv][2];
    cxd* R = (cxd*)scr[wv][3];
    if (act){
      if (t < 10){
        double l = lam[t];   // Q = -0.5*(a - ad)
        for (int e=lane; e<100; e+=64){
          int i=e/10, j=e-10*i;
          double v = 0.0;
          if (j == i+1) v = -0.5*l*sqrt((double)(i+1));
          else if (i == j+1) v = 0.5*l*sqrt((double)i);
          M[e] = {v, 0.0};
        }
      } else if (t < 29){
        for (int e=lane; e<n*n; e+=64){
          int rr=e/n, c=e-n*rr;
          double v = 0.0;
          if (c == rr+1) v = THETA*sqrt((double)((ilo+rr+1)*(bn-ilo-rr)));
          else if (rr == c+1) v = THETA*sqrt((double)((ilo+c+1)*(bn-ilo-c)));
          M[e] = {0.0, v};
        }
      } else {
        int idx = t-29, kind = idx>>3, L=(idx>>2)&1, w=idx&3;
        double r_ = kind ? (double)dmag[L*4+w]   : (double)smag[L*4+w];
        double ph = kind ? (double)dphase[L*4+w] : (double)sphase[L*4+w];
        double zr = r_*cos(ph), zi = r_*sin(ph);
        for (int e=lane; e<100; e+=64){
          int i=e/10, j=e-10*i;
          M[e] = kind ? gen_disp(i,j,zr,zi) : gen_squeeze(i,j,zr,zi);
        }
      }
    }
    __syncthreads();
    expm_fixed(act, n, M, P, T, R, lane);
    if (act){
      if (t < 10){
        for (int e=lane;e<100;e+=64){
          int i=e/10, j=e-10*i;
          float w = (float)R[e].x;
          ws_Wp[t*200 + (j*10+i)*2 + 0] = w;    // transposed + splat
          ws_Wp[t*200 + (j*10+i)*2 + 1] = w;
        }
      } else if (t < 29){
        for (int e=lane;e<100;e+=64){
          int rr=e/10, c=e-10*rr;
          float ux=0.f, uy=0.f;
          if (rr < n && c < n){ ux=(float)R[rr*n+c].x; uy=(float)R[rr*n+c].y; }
          float* dst = ws_BS4 + (bn*100 + c*10 + rr)*4;   // transposed + padded
          dst[0]=ux; dst[1]=ux; dst[2]=-uy; dst[3]=uy;
        }
      } else {
        int idx = t-29;
        cxd* dst = (cxd*)layres[idx];
        for (int e=lane;e<100;e+=64) dst[e] = R[e];
      }
    }
    __syncthreads();
  }

  if (g == 7){
    for (int half=0; half<2; ++half){
      int f = wv + half*4;
      cxd* D  = (cxd*)layres[8+f];
      cxd* Sm = (cxd*)layres[f];
      cxd* prod = (cxd*)scr[wv][0];
      for (int e=lane;e<100;e+=64){
        int i=e/10, j=e-10*i;
        double ax=0, ay=0;
        for (int k=0;k<10;k++){
          cxd d=D[i*10+k], s=Sm[k*10+j];
          ax += d.x*s.x - d.y*s.y;
          ay += d.x*s.y + d.y*s.x;
        }
        prod[e] = {ax, ay};
      }
      __syncthreads();
      for (int e=lane;e<100;e+=64){
        int i=e/10, j=e-10*i;
        double ox, oy;
        if (f == 0){
          ox = 0; oy = 0;
          for (int k=0;k<10;k++){
            double v = Vd[k*10+i];
            ox += v*prod[k*10+j].x;
            oy += v*prod[k*10+j].y;
          }
        } else { ox = prod[e].x; oy = prod[e].y; }
        float* dst = ws_UL4 + (f*100 + j*10 + i)*4;       // transposed
        dst[0]=(float)ox; dst[1]=(float)ox; dst[2]=(float)(-oy); dst[3]=(float)oy;
      }
      __syncthreads();
    }
  }
}

// ------------- Kernel B: per-(b,w) encoding vector u = D*(S*e0) ------------
__global__ __launch_bounds__(128)
void enc_kernel(const float* __restrict__ jets, const float* __restrict__ sscale,
                float* __restrict__ wsf){
  __shared__ double scr[2][4][200];
  __shared__ double col[20];
  __shared__ double uacc[20];
  const int tid = threadIdx.x, wv = tid>>6, lane = tid&63;
  const int blk = blockIdx.x, b = blk>>2, w = blk&3;

  double eta = (double)jets[b*12 + w*3 + 0];
  double jph = (double)jets[b*12 + w*3 + 1];
  double pt  = (double)jets[b*12 + w*3 + 2];

  cxd* M = (cxd*)scr[wv][0];
  cxd* P = (cxd*)scr[wv][1];
  cxd* T = (cxd*)scr[wv][2];
  cxd* R = (cxd*)scr[wv][3];
  {
    double zr, zi;
    if (wv == 0){ double phs = pt*jph*0.5; zr = eta*cos(phs); zi = eta*sin(phs); }
    else {
      double sc = 10.0/(1.0 + exp(-(double)sscale[0])) + 0.01;
      double mag = sc*pt; zr = mag*cos(eta); zi = mag*sin(eta);
    }
    for (int e=lane; e<100; e+=64){
      int i=e/10, j=e-10*i;
      M[e] = wv ? gen_disp(i,j,zr,zi) : gen_squeeze(i,j,zr,zi);
    }
  }
  __syncthreads();
  expm_fixed(true, 10, M, P, T, R, lane);
  cxd* Rs = (cxd*)scr[0][3];
  cxd* Rd = (cxd*)scr[1][3];
  if (tid < 10){ col[2*tid] = Rs[tid*10].x; col[2*tid+1] = Rs[tid*10].y; }
  __syncthreads();
  if (tid < 10){
    double ax=0, ay=0;
    for (int k=0;k<10;k++){
      cxd d = Rd[tid*10+k];
      double cr = col[2*k], ci = col[2*k+1];
      ax += d.x*cr - d.y*ci;
      ay += d.x*ci + d.y*cr;
    }
    uacc[2*tid] = ax; uacc[2*tid+1] = ay;
  }
  __syncthreads();
  if (tid < 10){
    double rx, ry;
    if (w == 0){
      rx = 0; ry = 0;
      for (int k=0;k<10;k++){
        double v = (double)wsf[(k*10 + tid)*2];   // Vp .x plane = V[k][tid]
        rx += v*uacc[2*k];
        ry += v*uacc[2*k+1];
      }
    } else { rx = uacc[2*tid]; ry = uacc[2*tid+1]; }
    float* u_out = wsf + 13568 + (b*40 + w*10 + tid)*2;
    u_out[0] = (float)rx;
    u_out[1] = (float)ry;
  }
}

// ---------------- Kernel C: the circuit, state-only LDS --------------------
// Named v2f accumulators; pre-shaped tables -> zero operand-construction VALU.

#define DECL_ACCP \
  v2f a0={0.f,0.f}, a1={0.f,0.f}, a2={0.f,0.f}, a3={0.f,0.f}, a4={0.f,0.f}, \
      a5={0.f,0.f}, a6={0.f,0.f}, a7={0.f,0.f}, a8={0.f,0.f}, a9={0.f,0.f};

// complex: table float4 q = (ux,ux,-uy,uy): 2 pk-fma, no shuffles
#define CKP(i) { v4f q = *(const v4f*)(U4 + (kk+(i))*4); \
  a##i = __builtin_elementwise_fma((v2f){q.x,q.y}, vv, a##i); \
  a##i = __builtin_elementwise_fma((v2f){q.z,q.w}, vs, a##i); }
// real: table v2f (w,w): 1 pk-fma
#define RKP(i) { v2f u = *(const v2f*)(Mt2 + (kk+(i))*2); \
  a##i = __builtin_elementwise_fma(u, vv, a##i); }
#define BKP(r) { v4f q = *(const v4f*)(Bt4 + (kk+(r))*4); \
  a##r = __builtin_elementwise_fma((v2f){q.x,q.y}, vv, a##r); \
  a##r = __builtin_elementwise_fma((v2f){q.z,q.w}, vs, a##r); }

#define PSTORE(i) { *(v2f*)&S[base + (i)*sm] = a##i; }
#define PALLSTORE PSTORE(0) PSTORE(1) PSTORE(2) PSTORE(3) PSTORE(4) PSTORE(5) PSTORE(6) PSTORE(7) PSTORE(8) PSTORE(9)
#define BPSTORE(r) if ((r) < sz){ *(v2f*)&S[wadr] = a##r; wadr += ds; }
#define BPALLSTORE BPSTORE(0) BPSTORE(1) BPSTORE(2) BPSTORE(3) BPSTORE(4) BPSTORE(5) BPSTORE(6) BPSTORE(7) BPSTORE(8) BPSTORE(9)

// Single-mode complex gate (m compile-time after inlining).
__device__ __forceinline__ void apply1_c(cxf* S, const float* __restrict__ U4, int m, int tid){
  const int sm = (m==0)?1000:((m==1)?100:((m==2)?10:1));
  const int r0 = (m==0)?1:0, r1=(m<=1)?2:1, r2=(m<=2)?3:2;
  const int s0 = (r0==0)?1000:((r0==1)?100:((r0==2)?10:1));
  const int s1 = (r1==0)?1000:((r1==1)?100:((r1==2)?10:1));
  const int s2 = (r2==0)?1000:((r2==1)?100:((r2==2)?10:1));
  int f = tid;
  if (f < 1000){
    int c0=f/100, rem=f-100*c0, c1=rem/10, c2=rem-10*c1;
    int base = c0*s0 + c1*s1 + c2*s2;
    DECL_ACCP
    #pragma unroll 2
    for (int k=0;k<10;k++){
      v2f vv = *(const v2f*)&S[base + k*sm];
      v2f vs = {vv.y, vv.x};
      int kk = k*10;
      CKP(0) CKP(1) CKP(2) CKP(3) CKP(4) CKP(5) CKP(6) CKP(7) CKP(8) CKP(9)
    }
    PALLSTORE
  }
}

// Single-mode real gate. Pass Vp for the V^T gate, VTp for V.
__device__ __forceinline__ void apply1_r(cxf* S, const float* __restrict__ Mt2, int m, int tid){
  const int sm = (m==0)?1000:((m==1)?100:((m==2)?10:1));
  const int r0 = (m==0)?1:0, r1=(m<=1)?2:1, r2=(m<=2)?3:2;
  const int s0 = (r0==0)?1000:((r0==1)?100:((r0==2)?10:1));
  const int s1 = (r1==0)?1000:((r1==1)?100:((r1==2)?10:1));
  const int s2 = (r2==0)?1000:((r2==1)?100:((r2==2)?10:1));
  int f = tid;
  if (f < 1000){
    int c0=f/100, rem=f-100*c0, c1=rem/10, c2=rem-10*c1;
    int base = c0*s0 + c1*s1 + c2*s2;
    DECL_ACCP
    #pragma unroll 2
    for (int k=0;k<10;k++){
      v2f vv = *(const v2f*)&S[base + k*sm];
      int kk = k*10;
      RKP(0) RKP(1) RKP(2) RKP(3) RKP(4) RKP(5) RKP(6) RKP(7) RKP(8) RKP(9)
    }
    PALLSTORE
  }
}

// Conditional real gate on m2, W[n] selected by m1 digit (fiber MSD -> uniform n).
__device__ __forceinline__ void applyW(cxf* S, const float* __restrict__ Wall, int m1, int m2, int tid){
  const int sm  = (m2==0)?1000:((m2==1)?100:((m2==2)?10:1));
  const int sm1 = (m1==0)?1000:((m1==1)?100:((m1==2)?10:1));
  int ra=-1, rb=-1;
  for (int q=0;q<4;q++) if (q!=m1 && q!=m2){ if (ra<0) ra=q; else rb=q; }
  const int sa = (ra==0)?1000:((ra==1)?100:((ra==2)?10:1));
  const int sb = (rb==0)?1000:((rb==1)?100:((rb==2)?10:1));
  int f = tid;
  if (f < 1000){
    int n = f/100, rem = f-100*n, qa = rem/10, qb = rem-10*qa;
    int base = n*sm1 + qa*sa + qb*sb;
    const float* __restrict__ Mt2 = Wall + n*200;   // transposed, splat pairs
    DECL_ACCP
    #pragma unroll 2
    for (int k=0;k<10;k++){
      v2f vv = *(const v2f*)&S[base + k*sm];
      int kk = k*10;
      RKP(0) RKP(1) RKP(2) RKP(3) RKP(4) RKP(5) RKP(6) RKP(7) RKP(8) RKP(9)
    }
    PALLSTORE
  }
}

// Beamsplitter via total-photon blocks; ragged c-loop, address recurrence.
__device__ __forceinline__ void applyBS(cxf* S, const float* __restrict__ BSp4, int m1, int m2, int tid){
  int ra=-1, rb=-1;
  for (int q=0;q<4;q++) if (q!=m1 && q!=m2){ if (ra<0) ra=q; else rb=q; }
  const int sa = (ra==0)?1000:((ra==1)?100:((ra==2)?10:1));
  const int sb = (rb==0)?1000:((rb==1)?100:((rb==2)?10:1));
  const int s1 = (m1==0)?1000:((m1==1)?100:((m1==2)?10:1));
  const int s2 = (m2==0)?1000:((m2==1)?100:((m2==2)?10:1));
  const int ds = s1 - s2;
  #pragma unroll 1
  for (int w0=0; w0<2048; w0+=NTB){
    int it = w0 + tid;
    if (it < 1900){
      int bn = it/100, rest = it-100*bn;
      int ilo = bn<10?0:bn-9, ihi = bn<10?bn:9, sz = ihi-ilo+1;
      int ca = rest/10, cb = rest-10*ca;
      int base = ca*sa + cb*sb;
      const float* __restrict__ Bt4 = BSp4 + bn*400;  // transposed, float4
      DECL_ACCP
      int radr = base + ilo*s1 + (bn-ilo)*s2;         // element (ilo+c, bn-ilo-c)
      int kk = 0;
      #pragma unroll 1
      for (int c=0;c<sz;c++){
        v2f vv = *(const v2f*)&S[radr];
        v2f vs = {vv.y, vv.x};
        BKP(0) BKP(1) BKP(2) BKP(3) BKP(4) BKP(5) BKP(6) BKP(7) BKP(8) BKP(9)
        radr += ds; kk += 10;
      }
      int wadr = base + ilo*s1 + (bn-ilo)*s2;
      BPALLSTORE
    }
  }
}

__global__ __launch_bounds__(NTB)
__attribute__((amdgpu_waves_per_eu(8)))
void state_kernel(const float* __restrict__ wd, const float* __restrict__ bd,
                  const float* __restrict__ wsf, float* __restrict__ out){
  extern __shared__ __align__(16) char smem[];
  cxf* S    = (cxf*)smem;                 // 10000 cxf (80000 B)
  cxf* uv   = (cxf*)(smem + 80000);       // 4*10 encoding vectors
  float* red = (float*)(smem + 80320);    // 16

  const float* __restrict__ Vp  = wsf;            // splat pairs, V^T gate
  const float* __restrict__ VTp = wsf + 256;      // splat pairs, V gate
  const float* __restrict__ Wp  = wsf + 512;
  const float* __restrict__ BS4 = wsf + 2560;
  const float* __restrict__ UL4 = wsf + 10240;
  const cxf*   __restrict__ uw  = (const cxf*)(wsf + 13568);

  const int tid = threadIdx.x, wv = tid>>6, lane = tid&63;
  const int b = blockIdx.x;

  if (tid < 40) uv[tid] = uw[b*40 + tid];
  __syncthreads();

  // Init: product state S = u0 (x) u1 (x) u2 (x) u3  (V0^T already folded in u0)
  for (int e=tid; e<10000; e+=NTB){
    int c0=e/1000, r_=e-1000*c0, c1=r_/100, r2_=r_-100*c1, c2=r2_/10, c3=r2_-10*c2;
    cxf A = uv[c0], B = uv[10+c1], C = uv[20+c2], D = uv[30+c3];
    float pr = A.x*B.x - A.y*B.y, pi = A.x*B.y + A.y*B.x;
    float qr = pr*C.x - pi*C.y,  qi = pr*C.y + pi*C.x;
    cxf o; o.x = qr*D.x - qi*D.y; o.y = qr*D.y + qi*D.x;
    S[e] = o;
  }
  __syncthreads();

  for (int L=0; L<2; ++L){
    // CX group a=0 (V0^T folded into u0 / UL[0]):
    applyW(S, Wp, 0, 1, tid); __syncthreads();
    applyW(S, Wp, 0, 2, tid); __syncthreads();
    applyW(S, Wp, 0, 3, tid); __syncthreads();
    apply1_r(S, VTp, 0, tid); __syncthreads();     // V gate
    // a=1:
    apply1_r(S, Vp, 1, tid);  __syncthreads();     // V^T gate
    applyW(S, Wp, 1, 2, tid); __syncthreads();
    applyW(S, Wp, 1, 3, tid); __syncthreads();
    apply1_r(S, VTp, 1, tid); __syncthreads();
    // a=2:
    apply1_r(S, Vp, 2, tid);  __syncthreads();
    applyW(S, Wp, 2, 3, tid); __syncthreads();
    apply1_r(S, VTp, 2, tid); __syncthreads();
    // Beamsplitters:
    applyBS(S, BS4, 0, 1, tid); __syncthreads();
    applyBS(S, BS4, 1, 2, tid); __syncthreads();
    applyBS(S, BS4, 2, 3, tid); __syncthreads();
    applyBS(S, BS4, 3, 0, tid); __syncthreads();
    // Layer single-mode gates (UL[0] carries next layer's V0^T):
    for (int w=0; w<4; ++w){ apply1_c(S, UL4 + (L*4+w)*400, w, tid); __syncthreads(); }
  }

  float w0 = wd[0], w1 = wd[1], w2 = wd[2];
  float acc = 0.f;
  for (int e=tid; e<10000; e+=NTB){
    cxf z = S[e];
    float p = z.x*z.x + z.y*z.y;
    int n0 = e/1000, r_ = e-1000*n0, n1 = r_/100, r2_ = r_-100*n1, n2 = r2_/10;
    acc += p * ((float)n0*w0 + (float)n1*w1 + (float)n2*w2);
  }
  for (int off=32; off; off>>=1) acc += __shfl_down(acc, off, 64);
  if (lane == 0) red[wv] = acc;
  __syncthreads();
  if (tid == 0){
    float s = 0.f;
    for (int i=0;i<16;i++) s += red[i];
    out[b] = s + bd[0];
  }
}

} // anonymous namespace

extern "C" void kernel_launch(void* const* d_in, const int* in_sizes, int n_in,
                              void* d_out, int out_size, void* d_ws, size_t ws_size,
                              hipStream_t stream){
  const float* jets   = (const float*)d_in[0];
  const float* sscale = (const float*)d_in[1];
  const float* dmag   = (const float*)d_in[2];
  const float* dphase = (const float*)d_in[3];
  const float* smag   = (const float*)d_in[4];
  const float* sphase = (const float*)d_in[5];
  const float* wd     = (const float*)d_in[6];
  const float* bd     = (const float*)d_in[7];
  float* out = (float*)d_out;
  float* wsf = (float*)d_ws;
  int B = in_sizes[0] / 12;

  (void)hipFuncSetAttribute(reinterpret_cast<const void*>(&state_kernel),
                            hipFuncAttributeMaxDynamicSharedMemorySize, SMEM_BYTES);

  gates_kernel<<<8, 256, 0, stream>>>(dmag, dphase, smag, sphase, wsf);
  enc_kernel<<<B*4, 128, 0, stream>>>(jets, sscale, wsf);
  state_kernel<<<B, NTB, SMEM_BYTES, stream>>>(wd, bd, wsf, out);
}

// Round 11
// 1398.767 us; speedup vs baseline: 1.3620x; 1.3620x over previous
//
#include <hip/hip_runtime.h>
#include <math.h>

// CV-photonic circuit: WIRES=4, LAYERS=2, CUTOFF=10, BATCH=2048.
// R11 = R9 (compact tables, 967us) + inline-asm v_pk_fma_f32 using
// op_sel/op_sel_hi/neg_lo so complex (i,k) = 1x 8B load + 2 pk-fma and
// real (i,k) = 0.5x 8B load + 1 pk-fma, with ZERO operand-construction VALU.
// R10's pre-shaped 52KB tables thrashed L1 (VALUBusy 60->32%) — reverted.

namespace {

constexpr int NTB = 1024;                // threads per state block (16 waves)
constexpr int SMEM_BYTES = 80384;        // state 80000 + uv 320 + red 64
constexpr double THETA = 0.7853981633974483096; // pi/4

struct cxf { float x, y; };
struct cxd { double x, y; };
typedef float v2f __attribute__((ext_vector_type(2)));

// ws float layout (matrices stored TRANSPOSED for k-outer consumption):
// [0,100)      V    (V[k*10+m]; used directly for the V^T gate)
// [100,200)    VT   (VT[k*10+i] = V[i][k]; used for the V gate)
// [200,1200)   Wt   (10 real 10x10, per-n transposed: Wt[n*100+k*10+i]=W_n[i][k])
// [1200,5000)  BSt  cxf[19*100] zero-padded, transposed: BSt[bn*100+c*10+r]
// [5000,6600)  ULt  cxf[8*100] fused layer gates, transposed
// [6656,...)   u    cxf[B*4*10] encoded per-(b,w) vectors

__device__ __forceinline__ cxd gen_squeeze(int i, int j, double zr, double zi){
  if (j == i+2){ double g = 0.5*sqrt((double)((i+1)*(i+2))); return {zr*g, -zi*g}; }
  if (i == j+2){ double g = 0.5*sqrt((double)((j+1)*(j+2))); return {-zr*g, -zi*g}; }
  return {0.0, 0.0};
}
__device__ __forceinline__ cxd gen_disp(int i, int j, double ar, double ai){
  if (i == j+1){ double g = sqrt((double)i); return {ar*g, ai*g}; }
  if (j == i+1){ double g = sqrt((double)j); return {-ar*g, ai*g}; }
  return {0.0, 0.0};
}

// Wave-cooperative fixed-schedule expm: result = exp(M), n x n (n<=10).
__device__ void expm_fixed(bool act, int n, cxd* M, cxd* P, cxd* T, cxd* R, int lane){
  const int n2 = n*n;
  if (act){
    for (int e=lane; e<n2; e+=64){ M[e].x *= 0x1p-10; M[e].y *= 0x1p-10; }
    for (int e=lane; e<n2; e+=64){
      P[e] = M[e];
      cxd r = M[e];
      if (e % (n+1) == 0) r.x += 1.0;
      R[e] = r;
    }
  }
  __syncthreads();
  for (int t=2; t<=12; ++t){
    if (act){
      double inv = 1.0/(double)t;
      for (int e=lane; e<n2; e+=64){
        int i = e/n, j = e - i*n;
        double ax=0.0, ay=0.0;
        for (int k=0;k<n;k++){
          cxd p = P[i*n+k], m = M[k*n+j];
          ax += p.x*m.x - p.y*m.y;
          ay += p.x*m.y + p.y*m.x;
        }
        T[e] = {ax*inv, ay*inv};
      }
    }
    __syncthreads();
    { cxd* tmp = P; P = T; T = tmp; }
    if (act){ for (int e=lane; e<n2; e+=64){ R[e].x += P[e].x; R[e].y += P[e].y; } }
    __syncthreads();
  }
  for (int s=0; s<10; ++s){
    if (act){
      for (int e=lane; e<n2; e+=64){
        int i = e/n, j = e - i*n;
        double ax=0.0, ay=0.0;
        for (int k=0;k<n;k++){
          cxd p = R[i*n+k], q = R[k*n+j];
          ax += p.x*q.x - p.y*q.y;
          ay += p.x*q.y + p.y*q.x;
        }
        T[e] = {ax, ay};
      }
    }
    __syncthreads();
    { cxd* tmp = R; R = T; T = tmp; }
    __syncthreads();
  }
}

// ------------- Kernel A: shared gate tables into d_ws (8 blocks) -----------
__global__ __launch_bounds__(256)
void gates_kernel(const float* __restrict__ dmag, const float* __restrict__ dphase,
                  const float* __restrict__ smag, const float* __restrict__ sphase,
                  float* __restrict__ wsf){
  __shared__ double lam[10];
  __shared__ double Vd[100];
  __shared__ double scr[4][4][200];     // [wave][buf] cxd[100]
  __shared__ double layres[16][200];    // S_lay (0..7), D_lay (8..15)
  const int tid = threadIdx.x;
  const int wv = tid >> 6, lane = tid & 63, g = blockIdx.x;
  float* ws_V  = wsf;
  float* ws_VT = wsf + 100;
  float* ws_W  = wsf + 200;
  cxf* ws_BS = (cxf*)(wsf + 1200);
  cxf* ws_UL = (cxf*)(wsf + 5000);

  if (tid < 10){
    double lo = -6.0, hi = 6.0;
    for (int it=0; it<80; ++it){
      double mid = 0.5*(lo+hi);
      int cnt = 0; double q = 1.0;
      for (int i=0;i<10;i++){
        q = -mid - (i ? (double)i/q : 0.0);
        if (fabs(q) < 1e-300) q = -1e-300;
        if (q < 0.0) cnt++;
      }
      if (cnt > tid) hi = mid; else lo = mid;
    }
    double x = 0.5*(lo+hi);
    double p[10];
    p[0] = 1.0; p[1] = x;
    for (int k=1;k<9;k++) p[k+1] = (x*p[k] - sqrt((double)k)*p[k-1]) * (1.0/sqrt((double)(k+1)));
    double nn=0.0; for (int k=0;k<10;k++) nn += p[k]*p[k];
    double inv = 1.0/sqrt(nn);
    lam[tid] = x;
    for (int k=0;k<10;k++){
      Vd[k*10+tid] = p[k]*inv;
      if (g == 0){
        ws_V[k*10+tid]  = (float)(p[k]*inv);
        ws_VT[tid*10+k] = (float)(p[k]*inv);
      }
    }
  }
  __syncthreads();

  const int nrounds = (g==7) ? 5 : 1;
  for (int r=0; r<nrounds; ++r){
    int t;
    if (g < 7) t = 4*g + wv;
    else       t = (r==0) ? ((wv==0) ? 28 : 64) : (29 + (r-1)*4 + wv);
    bool act = (t < 45);
    int n = 10, bn = 0, ilo = 0;
    if (act && t >= 10 && t < 29){
      bn = t - 10; ilo = bn < 10 ? 0 : bn - 9;
      int ihi = bn < 10 ? bn : 9;
      n = ihi - ilo + 1;
    }
    cxd* M = (cxd*)scr[wv][0];
    cxd* P = (cxd*)scr[wv][1];
    cxd* T = (cxd*)scr[wv][2];
    cxd* R = (cxd*)scr[wv][3];
    if (act){
      if (t < 10){
        double l = lam[t];   // Q = -0.5*(a - ad)
        for (int e=lane; e<100; e+=64){
          int i=e/10, j=e-10*i;
          double v = 0.0;
          if (j == i+1) v = -0.5*l*sqrt((double)(i+1));
          else if (i == j+1) v = 0.5*l*sqrt((double)i);
          M[e] = {v, 0.0};
        }
      } else if (t < 29){
        for (int e=lane; e<n*n; e+=64){
          int rr=e/n, c=e-n*rr;
          double v = 0.0;
          if (c == rr+1) v = THETA*sqrt((double)((ilo+rr+1)*(bn-ilo-rr)));
          else if (rr == c+1) v = THETA*sqrt((double)((ilo+c+1)*(bn-ilo-c)));
          M[e] = {0.0, v};
        }
      } else {
        int idx = t-29, kind = idx>>3, L=(idx>>2)&1, w=idx&3;
        double r_ = kind ? (double)dmag[L*4+w]   : (double)smag[L*4+w];
        double ph = kind ? (double)dphase[L*4+w] : (double)sphase[L*4+w];
        double zr = r_*cos(ph), zi = r_*sin(ph);
        for (int e=lane; e<100; e+=64){
          int i=e/10, j=e-10*i;
          M[e] = kind ? gen_disp(i,j,zr,zi) : gen_squeeze(i,j,zr,zi);
        }
      }
    }
    __syncthreads();
    expm_fixed(act, n, M, P, T, R, lane);
    if (act){
      if (t < 10){
        for (int e=lane;e<100;e+=64){
          int i=e/10, j=e-10*i;
          ws_W[t*100 + j*10 + i] = (float)R[e].x;   // transposed
        }
      } else if (t < 29){
        for (int e=lane;e<100;e+=64){
          int rr=e/10, c=e-10*rr;
          cxf o; o.x=0.f; o.y=0.f;
          if (rr < n && c < n){ o.x=(float)R[rr*n+c].x; o.y=(float)R[rr*n+c].y; }
          ws_BS[bn*100 + c*10 + rr]=o;              // zero-padded + transposed
        }
      } else {
        int idx = t-29;
        cxd* dst = (cxd*)layres[idx];
        for (int e=lane;e<100;e+=64) dst[e] = R[e];
      }
    }
    __syncthreads();
  }

  if (g == 7){
    for (int half=0; half<2; ++half){
      int f = wv + half*4;
      cxd* D  = (cxd*)layres[8+f];
      cxd* Sm = (cxd*)layres[f];
      cxd* prod = (cxd*)scr[wv][0];
      for (int e=lane;e<100;e+=64){
        int i=e/10, j=e-10*i;
        double ax=0, ay=0;
        for (int k=0;k<10;k++){
          cxd d=D[i*10+k], s=Sm[k*10+j];
          ax += d.x*s.x - d.y*s.y;
          ay += d.x*s.y + d.y*s.x;
        }
        prod[e] = {ax, ay};
      }
      __syncthreads();
      for (int e=lane;e<100;e+=64){
        int i=e/10, j=e-10*i;
        double ox, oy;
        if (f == 0){
          ox = 0; oy = 0;
          for (int k=0;k<10;k++){
            double v = Vd[k*10+i];
            ox += v*prod[k*10+j].x;
            oy += v*prod[k*10+j].y;
          }
        } else { ox = prod[e].x; oy = prod[e].y; }
        cxf o; o.x=(float)ox; o.y=(float)oy;
        ws_UL[f*100 + j*10 + i] = o;                // transposed
      }
      __syncthreads();
    }
  }
}

// ------------- Kernel B: per-(b,w) encoding vector u = D*(S*e0) ------------
__global__ __launch_bounds__(128)
void enc_kernel(const float* __restrict__ jets, const float* __restrict__ sscale,
                float* __restrict__ wsf){
  __shared__ double scr[2][4][200];
  __shared__ double col[20];
  __shared__ double uacc[20];
  const int tid = threadIdx.x, wv = tid>>6, lane = tid&63;
  const int blk = blockIdx.x, b = blk>>2, w = blk&3;

  double eta = (double)jets[b*12 + w*3 + 0];
  double jph = (double)jets[b*12 + w*3 + 1];
  double pt  = (double)jets[b*12 + w*3 + 2];

  cxd* M = (cxd*)scr[wv][0];
  cxd* P = (cxd*)scr[wv][1];
  cxd* T = (cxd*)scr[wv][2];
  cxd* R = (cxd*)scr[wv][3];
  {
    double zr, zi;
    if (wv == 0){ double phs = pt*jph*0.5; zr = eta*cos(phs); zi = eta*sin(phs); }
    else {
      double sc = 10.0/(1.0 + exp(-(double)sscale[0])) + 0.01;
      double mag = sc*pt; zr = mag*cos(eta); zi = mag*sin(eta);
    }
    for (int e=lane; e<100; e+=64){
      int i=e/10, j=e-10*i;
      M[e] = wv ? gen_disp(i,j,zr,zi) : gen_squeeze(i,j,zr,zi);
    }
  }
  __syncthreads();
  expm_fixed(true, 10, M, P, T, R, lane);
  cxd* Rs = (cxd*)scr[0][3];
  cxd* Rd = (cxd*)scr[1][3];
  if (tid < 10){ col[2*tid] = Rs[tid*10].x; col[2*tid+1] = Rs[tid*10].y; }
  __syncthreads();
  if (tid < 10){
    double ax=0, ay=0;
    for (int k=0;k<10;k++){
      cxd d = Rd[tid*10+k];
      double cr = col[2*k], ci = col[2*k+1];
      ax += d.x*cr - d.y*ci;
      ay += d.x*ci + d.y*cr;
    }
    uacc[2*tid] = ax; uacc[2*tid+1] = ay;
  }
  __syncthreads();
  if (tid < 10){
    double rx, ry;
    if (w == 0){
      rx = 0; ry = 0;
      for (int k=0;k<10;k++){
        double v = (double)wsf[k*10 + tid];
        rx += v*uacc[2*k];
        ry += v*uacc[2*k+1];
      }
    } else { rx = uacc[2*tid]; ry = uacc[2*tid+1]; }
    float* u_out = wsf + 6656 + (b*40 + w*10 + tid)*2;
    u_out[0] = (float)rx;
    u_out[1] = (float)ry;
  }
}

// ---------------- Kernel C: the circuit, state-only LDS --------------------
// Named v2f accumulators; inline-asm v_pk_fma_f32 with op_sel/neg_lo:
//  real pair (i,i+1): 1x 8B load + 2 pk-fma (lo/lo and hi/hi splat)
//  complex (i,k):     1x 8B load u=(ux,uy) + 2 pk-fma
//    term1: (ux,ux)*(vx,vy): op_sel:[0,0,0] op_sel_hi:[0,1,1]
//    term2: (-uy,uy)*(vy,vx): op_sel:[1,1,0] op_sel_hi:[1,0,1] neg_lo:[1,0,0]

#define DECL_ACCP \
  v2f a0={0.f,0.f}, a1={0.f,0.f}, a2={0.f,0.f}, a3={0.f,0.f}, a4={0.f,0.f}, \
      a5={0.f,0.f}, a6={0.f,0.f}, a7={0.f,0.f}, a8={0.f,0.f}, a9={0.f,0.f};

#define RK2(i,j) { v2f t = *(const v2f*)(Mt + kk + (i)); \
  asm("v_pk_fma_f32 %0, %1, %2, %0 op_sel:[0,0,0] op_sel_hi:[0,1,1]" \
      : "+v"(a##i) : "v"(t), "v"(vv)); \
  asm("v_pk_fma_f32 %0, %1, %2, %0 op_sel:[1,0,0] op_sel_hi:[1,1,1]" \
      : "+v"(a##j) : "v"(t), "v"(vv)); }
#define RALL RK2(0,1) RK2(2,3) RK2(4,5) RK2(6,7) RK2(8,9)

#define CK1(i) { v2f u = *(const v2f*)&U[kk+(i)]; \
  asm("v_pk_fma_f32 %0, %1, %2, %0 op_sel:[0,0,0] op_sel_hi:[0,1,1]" \
      : "+v"(a##i) : "v"(u), "v"(vv)); \
  asm("v_pk_fma_f32 %0, %1, %2, %0 op_sel:[1,1,0] op_sel_hi:[1,0,1] neg_lo:[1,0,0]" \
      : "+v"(a##i) : "v"(u), "v"(vv)); }
#define CALL CK1(0) CK1(1) CK1(2) CK1(3) CK1(4) CK1(5) CK1(6) CK1(7) CK1(8) CK1(9)

#define BK1(r) { v2f u = *(const v2f*)&Bt[kk+(r)]; \
  asm("v_pk_fma_f32 %0, %1, %2, %0 op_sel:[0,0,0] op_sel_hi:[0,1,1]" \
      : "+v"(a##r) : "v"(u), "v"(vv)); \
  asm("v_pk_fma_f32 %0, %1, %2, %0 op_sel:[1,1,0] op_sel_hi:[1,0,1] neg_lo:[1,0,0]" \
      : "+v"(a##r) : "v"(u), "v"(vv)); }
#define BALL BK1(0) BK1(1) BK1(2) BK1(3) BK1(4) BK1(5) BK1(6) BK1(7) BK1(8) BK1(9)

#define PSTORE(i) { *(v2f*)&S[base + (i)*sm] = a##i; }
#define PALLSTORE PSTORE(0) PSTORE(1) PSTORE(2) PSTORE(3) PSTORE(4) PSTORE(5) PSTORE(6) PSTORE(7) PSTORE(8) PSTORE(9)
#define BPSTORE(r) if ((r) < sz){ *(v2f*)&S[wadr] = a##r; wadr += ds; }
#define BPALLSTORE BPSTORE(0) BPSTORE(1) BPSTORE(2) BPSTORE(3) BPSTORE(4) BPSTORE(5) BPSTORE(6) BPSTORE(7) BPSTORE(8) BPSTORE(9)

// Single-mode complex gate (m compile-time after inlining).
__device__ __forceinline__ void apply1_c(cxf* S, const cxf* __restrict__ U, int m, int tid){
  const int sm = (m==0)?1000:((m==1)?100:((m==2)?10:1));
  const int r0 = (m==0)?1:0, r1=(m<=1)?2:1, r2=(m<=2)?3:2;
  const int s0 = (r0==0)?1000:((r0==1)?100:((r0==2)?10:1));
  const int s1 = (r1==0)?1000:((r1==1)?100:((r1==2)?10:1));
  const int s2 = (r2==0)?1000:((r2==1)?100:((r2==2)?10:1));
  int f = tid;
  if (f < 1000){
    int c0=f/100, rem=f-100*c0, c1=rem/10, c2=rem-10*c1;
    int base = c0*s0 + c1*s1 + c2*s2;
    DECL_ACCP
    #pragma unroll 2
    for (int k=0;k<10;k++){
      v2f vv = *(const v2f*)&S[base + k*sm];
      int kk = k*10;
      CALL
    }
    PALLSTORE
  }
}

// Single-mode real gate. Pass ws_V for the V^T gate, ws_VT for V.
__device__ __forceinline__ void apply1_r(cxf* S, const float* __restrict__ Mt, int m, int tid){
  const int sm = (m==0)?1000:((m==1)?100:((m==2)?10:1));
  const int r0 = (m==0)?1:0, r1=(m<=1)?2:1, r2=(m<=2)?3:2;
  const int s0 = (r0==0)?1000:((r0==1)?100:((r0==2)?10:1));
  const int s1 = (r1==0)?1000:((r1==1)?100:((r1==2)?10:1));
  const int s2 = (r2==0)?1000:((r2==1)?100:((r2==2)?10:1));
  int f = tid;
  if (f < 1000){
    int c0=f/100, rem=f-100*c0, c1=rem/10, c2=rem-10*c1;
    int base = c0*s0 + c1*s1 + c2*s2;
    DECL_ACCP
    #pragma unroll 2
    for (int k=0;k<10;k++){
      v2f vv = *(const v2f*)&S[base + k*sm];
      int kk = k*10;
      RALL
    }
    PALLSTORE
  }
}

// Conditional real gate on m2, W[n] selected by m1 digit (fiber MSD -> uniform n).
__device__ __forceinline__ void applyW(cxf* S, const float* __restrict__ Wall, int m1, int m2, int tid){
  const int sm  = (m2==0)?1000:((m2==1)?100:((m2==2)?10:1));
  const int sm1 = (m1==0)?1000:((m1==1)?100:((m1==2)?10:1));
  int ra=-1, rb=-1;
  for (int q=0;q<4;q++) if (q!=m1 && q!=m2){ if (ra<0) ra=q; else rb=q; }
  const int sa = (ra==0)?1000:((ra==1)?100:((ra==2)?10:1));
  const int sb = (rb==0)?1000:((rb==1)?100:((rb==2)?10:1));
  int f = tid;
  if (f < 1000){
    int n = f/100, rem = f-100*n, qa = rem/10, qb = rem-10*qa;
    int base = n*sm1 + qa*sa + qb*sb;
    const float* __restrict__ Mt = Wall + n*100;   // transposed W_n
    DECL_ACCP
    #pragma unroll 2
    for (int k=0;k<10;k++){
      v2f vv = *(const v2f*)&S[base + k*sm];
      int kk = k*10;
      RALL
    }
    PALLSTORE
  }
}

// Beamsplitter via total-photon blocks; ragged c-loop, address recurrence.
__device__ __forceinline__ void applyBS(cxf* S, const cxf* __restrict__ BSp, int m1, int m2, int tid){
  int ra=-1, rb=-1;
  for (int q=0;q<4;q++) if (q!=m1 && q!=m2){ if (ra<0) ra=q; else rb=q; }
  const int sa = (ra==0)?1000:((ra==1)?100:((ra==2)?10:1));
  const int sb = (rb==0)?1000:((rb==1)?100:((rb==2)?10:1));
  const int s1 = (m1==0)?1000:((m1==1)?100:((m1==2)?10:1));
  const int s2 = (m2==0)?1000:((m2==1)?100:((m2==2)?10:1));
  const int ds = s1 - s2;
  #pragma unroll 1
  for (int w0=0; w0<2048; w0+=NTB){
    int it = w0 + tid;
    if (it < 1900){
      int bn = it/100, rest = it-100*bn;
      int ilo = bn<10?0:bn-9, ihi = bn<10?bn:9, sz = ihi-ilo+1;
      int ca = rest/10, cb = rest-10*ca;
      int base = ca*sa + cb*sb;
      const cxf* __restrict__ Bt = BSp + bn*100;   // transposed
      DECL_ACCP
      int radr = base + ilo*s1 + (bn-ilo)*s2;      // element (ilo+c, bn-ilo-c)
      int kk = 0;
      #pragma unroll 1
      for (int c=0;c<sz;c++){
        v2f vv = *(const v2f*)&S[radr];
        BALL
        radr += ds; kk += 10;
      }
      int wadr = base + ilo*s1 + (bn-ilo)*s2;
      BPALLSTORE
    }
  }
}

__global__ __launch_bounds__(NTB)
__attribute__((amdgpu_waves_per_eu(8)))
void state_kernel(const float* __restrict__ wd, const float* __restrict__ bd,
                  const float* __restrict__ wsf, float* __restrict__ out){
  extern __shared__ __align__(16) char smem[];
  cxf* S    = (cxf*)smem;                 // 10000 cxf (80000 B)
  cxf* uv   = (cxf*)(smem + 80000);       // 4*10 encoding vectors
  float* red = (float*)(smem + 80320);    // 16

  const float* __restrict__ V   = wsf;            // for V^T gate
  const float* __restrict__ VT  = wsf + 100;      // for V gate
  const float* __restrict__ W   = wsf + 200;
  const cxf*   __restrict__ BSm = (const cxf*)(wsf + 1200);
  const cxf*   __restrict__ UL  = (const cxf*)(wsf + 5000);
  const cxf*   __restrict__ uw  = (const cxf*)(wsf + 6656);

  const int tid = threadIdx.x, wv = tid>>6, lane = tid&63;
  const int b = blockIdx.x;

  if (tid < 40) uv[tid] = uw[b*40 + tid];
  __syncthreads();

  // Init: product state S = u0 (x) u1 (x) u2 (x) u3  (V0^T already folded in u0)
  for (int e=tid; e<10000; e+=NTB){
    int c0=e/1000, r_=e-1000*c0, c1=r_/100, r2_=r_-100*c1, c2=r2_/10, c3=r2_-10*c2;
    cxf A = uv[c0], B = uv[10+c1], C = uv[20+c2], D = uv[30+c3];
    float pr = A.x*B.x - A.y*B.y, pi = A.x*B.y + A.y*B.x;
    float qr = pr*C.x - pi*C.y,  qi = pr*C.y + pi*C.x;
    cxf o; o.x = qr*D.x - qi*D.y; o.y = qr*D.y + qi*D.x;
    S[e] = o;
  }
  __syncthreads();

  for (int L=0; L<2; ++L){
    // CX group a=0 (V0^T folded into u0 / UL[0]):
    applyW(S, W, 0, 1, tid); __syncthreads();
    applyW(S, W, 0, 2, tid); __syncthreads();
    applyW(S, W, 0, 3, tid); __syncthreads();
    apply1_r(S, VT, 0, tid); __syncthreads();      // V gate
    // a=1:
    apply1_r(S, V, 1, tid);  __syncthreads();      // V^T gate
    applyW(S, W, 1, 2, tid); __syncthreads();
    applyW(S, W, 1, 3, tid); __syncthreads();
    apply1_r(S, VT, 1, tid); __syncthreads();
    // a=2:
    apply1_r(S, V, 2, tid);  __syncthreads();
    applyW(S, W, 2, 3, tid); __syncthreads();
    apply1_r(S, VT, 2, tid); __syncthreads();
    // Beamsplitters:
    applyBS(S, BSm, 0, 1, tid); __syncthreads();
    applyBS(S, BSm, 1, 2, tid); __syncthreads();
    applyBS(S, BSm, 2, 3, tid); __syncthreads();
    applyBS(S, BSm, 3, 0, tid); __syncthreads();
    // Layer single-mode gates (UL[0] carries next layer's V0^T):
    for (int w=0; w<4; ++w){ apply1_c(S, UL + (L*4+w)*100, w, tid); __syncthreads(); }
  }

  float w0 = wd[0], w1 = wd[1], w2 = wd[2];
  float acc = 0.f;
  for (int e=tid; e<10000; e+=NTB){
    cxf z = S[e];
    float p = z.x*z.x + z.y*z.y;
    int n0 = e/1000, r_ = e-1000*n0, n1 = r_/100, r2_ = r_-100*n1, n2 = r2_/10;
    acc += p * ((float)n0*w0 + (float)n1*w1 + (float)n2*w2);
  }
  for (int off=32; off; off>>=1) acc += __shfl_down(acc, off, 64);
  if (lane == 0) red[wv] = acc;
  __syncthreads();
  if (tid == 0){
    float s = 0.f;
    for (int i=0;i<16;i++) s += red[i];
    out[b] = s + bd[0];
  }
}

} // anonymous namespace

extern "C" void kernel_launch(void* const* d_in, const int* in_sizes, int n_in,
                              void* d_out, int out_size, void* d_ws, size_t ws_size,
                              hipStream_t stream){
  const float* jets   = (const float*)d_in[0];
  const float* sscale = (const float*)d_in[1];
  const float* dmag   = (const float*)d_in[2];
  const float* dphase = (const float*)d_in[3];
  const float* smag   = (const float*)d_in[4];
  const float* sphase = (const float*)d_in[5];
  const float* wd     = (const float*)d_in[6];
  const float* bd     = (const float*)d_in[7];
  float* out = (float*)d_out;
  float* wsf = (float*)d_ws;
  int B = in_sizes[0] / 12;

  (void)hipFuncSetAttribute(reinterpret_cast<const void*>(&state_kernel),
                            hipFuncAttributeMaxDynamicSharedMemorySize, SMEM_BYTES);

  gates_kernel<<<8, 256, 0, stream>>>(dmag, dphase, smag, sphase, wsf);
  enc_kernel<<<B*4, 128, 0, stream>>>(jets, sscale, wsf);
  state_kernel<<<B, NTB, SMEM_BYTES, stream>>>(wd, bd, wsf, out);
}

// Round 12
// 1117.399 us; speedup vs baseline: 1.7049x; 1.2518x over previous
//
#include <hip/hip_runtime.h>
#include <math.h>

// CV-photonic circuit: WIRES=4, LAYERS=2, CUTOFF=10, BATCH=2048.
// R12: state_kernel = R9 verbatim (best: 967us). Gap attack: gates_kernel
// 5 serial rounds -> 12 blocks x 1 round (45 expms parallel), UL fusion in a
// tiny fuse_kernel; all expm work fp64 -> fp32 (reference is complex64;
// Taylor-12 @ 2^-10 scaling error ~1e-22, fp32 rounding ~1e-6 << 3.6e-2).

namespace {

constexpr int NTB = 1024;                // threads per state block (16 waves)
constexpr int SMEM_BYTES = 80384;        // state 80000 + uv 320 + red 64
constexpr double THETA = 0.7853981633974483096; // pi/4

struct cxf { float x, y; };
typedef float v2f __attribute__((ext_vector_type(2)));

// ws float layout:
// [0,100)      V    (V[k*10+m]; used directly for the V^T gate)
// [100,200)    VT   (VT[k*10+i] = V[i][k]; used for the V gate)
// [200,1200)   Wt   (10 real 10x10, per-n transposed: Wt[n*100+k*10+i]=W_n[i][k])
// [1200,5000)  BSt  cxf[19*100] zero-padded, transposed: BSt[bn*100+c*10+r]
// [5000,6600)  ULt  cxf[8*100] fused layer gates, transposed
// [6600,9800)  stage cxf[16*100] raw S_lay (0..7) / D_lay (8..15)
// [9856,...)   u    cxf[B*4*10] encoded per-(b,w) vectors
constexpr int U_OFF = 9856;

__device__ __forceinline__ cxf gen_squeeze_f(int i, int j, float zr, float zi){
  if (j == i+2){ float g = 0.5f*sqrtf((float)((i+1)*(i+2))); return {zr*g, -zi*g}; }
  if (i == j+2){ float g = 0.5f*sqrtf((float)((j+1)*(j+2))); return {-zr*g, -zi*g}; }
  return {0.f, 0.f};
}
__device__ __forceinline__ cxf gen_disp_f(int i, int j, float ar, float ai){
  if (i == j+1){ float g = sqrtf((float)i); return {ar*g, ai*g}; }
  if (j == i+1){ float g = sqrtf((float)j); return {-ar*g, ai*g}; }
  return {0.f, 0.f};
}

// Wave-cooperative fixed-schedule fp32 expm: result = exp(M), n x n (n<=10).
// Result ends in the ORIGINAL R buffer (even number of swaps in each loop).
__device__ void expm_f32(bool act, int n, cxf* M, cxf* P, cxf* T, cxf* R, int lane){
  const int n2 = n*n;
  if (act){
    for (int e=lane; e<n2; e+=64){ M[e].x *= 0x1p-10f; M[e].y *= 0x1p-10f; }
    for (int e=lane; e<n2; e+=64){
      P[e] = M[e];
      cxf r = M[e];
      if (e % (n+1) == 0) r.x += 1.f;
      R[e] = r;
    }
  }
  __syncthreads();
  for (int t=2; t<=12; ++t){
    if (act){
      float inv = 1.f/(float)t;
      for (int e=lane; e<n2; e+=64){
        int i = e/n, j = e - i*n;
        float ax=0.f, ay=0.f;
        for (int k=0;k<n;k++){
          cxf p = P[i*n+k], m = M[k*n+j];
          ax += p.x*m.x - p.y*m.y;
          ay += p.x*m.y + p.y*m.x;
        }
        T[e] = {ax*inv, ay*inv};
      }
    }
    __syncthreads();
    { cxf* tmp = P; P = T; T = tmp; }
    if (act){ for (int e=lane; e<n2; e+=64){ R[e].x += P[e].x; R[e].y += P[e].y; } }
    __syncthreads();
  }
  for (int s=0; s<10; ++s){
    if (act){
      for (int e=lane; e<n2; e+=64){
        int i = e/n, j = e - i*n;
        float ax=0.f, ay=0.f;
        for (int k=0;k<n;k++){
          cxf p = R[i*n+k], q = R[k*n+j];
          ax += p.x*q.x - p.y*q.y;
          ay += p.x*q.y + p.y*q.x;
        }
        T[e] = {ax, ay};
      }
    }
    __syncthreads();
    { cxf* tmp = R; R = T; T = tmp; }
    __syncthreads();
  }
}

// ------------- Kernel A: 45 expm tasks fully parallel over 12 blocks -------
// Block g, wave wv: task t = 4g+wv (t<45). t<10: W[n]; 10..28: BS; 29..44:
// layer S/D staged raw to ws for fuse_kernel.
__global__ __launch_bounds__(256)
void gates_kernel(const float* __restrict__ dmag, const float* __restrict__ dphase,
                  const float* __restrict__ smag, const float* __restrict__ sphase,
                  float* __restrict__ wsf){
  __shared__ double lam[10];
  __shared__ float scr[4][4][200];      // [wave][buf] cxf[100]
  const int tid = threadIdx.x;
  const int wv = tid >> 6, lane = tid & 63, g = blockIdx.x;
  float* ws_V  = wsf;
  float* ws_VT = wsf + 100;
  float* ws_W  = wsf + 200;
  cxf* ws_BS   = (cxf*)(wsf + 1200);
  cxf* ws_stage= (cxf*)(wsf + 6600);

  // Eigen of x=a+ad: Sturm bisection (fp64, tiny). All blocks compute lam;
  // block 0 exports V/VT.
  if (tid < 10){
    double lo = -6.0, hi = 6.0;
    for (int it=0; it<80; ++it){
      double mid = 0.5*(lo+hi);
      int cnt = 0; double q = 1.0;
      for (int i=0;i<10;i++){
        q = -mid - (i ? (double)i/q : 0.0);
        if (fabs(q) < 1e-300) q = -1e-300;
        if (q < 0.0) cnt++;
      }
      if (cnt > tid) hi = mid; else lo = mid;
    }
    double x = 0.5*(lo+hi);
    double p[10];
    p[0] = 1.0; p[1] = x;
    for (int k=1;k<9;k++) p[k+1] = (x*p[k] - sqrt((double)k)*p[k-1]) * (1.0/sqrt((double)(k+1)));
    double nn=0.0; for (int k=0;k<10;k++) nn += p[k]*p[k];
    double inv = 1.0/sqrt(nn);
    lam[tid] = x;
    if (g == 0){
      for (int k=0;k<10;k++){
        float v = (float)(p[k]*inv);
        ws_V[k*10+tid]  = v;
        ws_VT[tid*10+k] = v;
      }
    }
  }
  __syncthreads();

  int t = g*4 + wv;
  bool act = (t < 45);
  int n = 10, bn = 0, ilo = 0;
  if (act && t >= 10 && t < 29){
    bn = t - 10; ilo = bn < 10 ? 0 : bn - 9;
    int ihi = bn < 10 ? bn : 9;
    n = ihi - ilo + 1;
  }
  cxf* M = (cxf*)scr[wv][0];
  cxf* P = (cxf*)scr[wv][1];
  cxf* T = (cxf*)scr[wv][2];
  cxf* R = (cxf*)scr[wv][3];
  if (act){
    if (t < 10){
      float l = (float)lam[t];   // Q = -0.5*(a - ad)
      for (int e=lane; e<100; e+=64){
        int i=e/10, j=e-10*i;
        float v = 0.f;
        if (j == i+1) v = -0.5f*l*sqrtf((float)(i+1));
        else if (i == j+1) v = 0.5f*l*sqrtf((float)i);
        M[e] = {v, 0.f};
      }
    } else if (t < 29){
      for (int e=lane; e<n*n; e+=64){
        int rr=e/n, c=e-n*rr;
        float v = 0.f;
        if (c == rr+1) v = (float)THETA*sqrtf((float)((ilo+rr+1)*(bn-ilo-rr)));
        else if (rr == c+1) v = (float)THETA*sqrtf((float)((ilo+c+1)*(bn-ilo-c)));
        M[e] = {0.f, v};
      }
    } else {
      int idx = t-29, kind = idx>>3, L=(idx>>2)&1, w=idx&3;
      float r_ = kind ? dmag[L*4+w]   : smag[L*4+w];
      float ph = kind ? dphase[L*4+w] : sphase[L*4+w];
      float zr = r_*cosf(ph), zi = r_*sinf(ph);
      for (int e=lane; e<100; e+=64){
        int i=e/10, j=e-10*i;
        M[e] = kind ? gen_disp_f(i,j,zr,zi) : gen_squeeze_f(i,j,zr,zi);
      }
    }
  }
  __syncthreads();
  expm_f32(act, n, M, P, T, R, lane);
  if (act){
    if (t < 10){
      for (int e=lane;e<100;e+=64){
        int i=e/10, j=e-10*i;
        ws_W[t*100 + j*10 + i] = R[e].x;   // transposed, real
      }
    } else if (t < 29){
      for (int e=lane;e<100;e+=64){
        int rr=e/10, c=e-10*rr;
        cxf o; o.x=0.f; o.y=0.f;
        if (rr < n && c < n) o = R[rr*n+c];
        ws_BS[bn*100 + c*10 + rr] = o;     // zero-padded + transposed
      }
    } else {
      int idx = t-29;
      for (int e=lane;e<100;e+=64) ws_stage[idx*100 + e] = R[e];
    }
  }
}

// ------------- Kernel A2: UL[f] = D_lay*S_lay (UL[0] left-mul V^T) ---------
__global__ __launch_bounds__(512)
void fuse_kernel(float* __restrict__ wsf){
  __shared__ cxf prod[8][100];
  const int tid = threadIdx.x, wv = tid>>6, lane = tid&63;
  const cxf* stage = (const cxf*)(wsf + 6600);
  cxf* ws_UL = (cxf*)(wsf + 5000);
  const float* V = wsf;
  const cxf* Sm = stage + wv*100;       // S_lay[f]
  const cxf* Dm = stage + (8+wv)*100;   // D_lay[f]
  for (int e=lane; e<100; e+=64){
    int i=e/10, j=e-10*i;
    float ax=0.f, ay=0.f;
    for (int k=0;k<10;k++){
      cxf d=Dm[i*10+k], s=Sm[k*10+j];
      ax += d.x*s.x - d.y*s.y;
      ay += d.x*s.y + d.y*s.x;
    }
    prod[wv][e] = {ax, ay};
  }
  __syncthreads();
  for (int e=lane; e<100; e+=64){
    int i=e/10, j=e-10*i;
    cxf o;
    if (wv == 0){
      float ox=0.f, oy=0.f;
      for (int k=0;k<10;k++){
        float v = V[k*10+i];              // (V^T)[i][k]
        ox += v*prod[0][k*10+j].x;
        oy += v*prod[0][k*10+j].y;
      }
      o = {ox, oy};
    } else o = prod[wv][e];
    ws_UL[wv*100 + j*10 + i] = o;        // transposed
  }
}

// ------------- Kernel B: per-(b,w) encoding vector u = D*(S*e0), fp32 ------
__global__ __launch_bounds__(128)
void enc_kernel(const float* __restrict__ jets, const float* __restrict__ sscale,
                float* __restrict__ wsf){
  __shared__ float scr[2][4][200];
  __shared__ cxf col[10];
  __shared__ cxf uacc[10];
  const int tid = threadIdx.x, wv = tid>>6, lane = tid&63;
  const int blk = blockIdx.x, b = blk>>2, w = blk&3;

  float eta = jets[b*12 + w*3 + 0];
  float jph = jets[b*12 + w*3 + 1];
  float pt  = jets[b*12 + w*3 + 2];

  cxf* M = (cxf*)scr[wv][0];
  cxf* P = (cxf*)scr[wv][1];
  cxf* T = (cxf*)scr[wv][2];
  cxf* R = (cxf*)scr[wv][3];
  {
    float zr, zi;
    if (wv == 0){ float phs = pt*jph*0.5f; zr = eta*cosf(phs); zi = eta*sinf(phs); }
    else {
      double sc = 10.0/(1.0 + exp(-(double)sscale[0])) + 0.01;
      float mag = (float)sc*pt; zr = mag*cosf(eta); zi = mag*sinf(eta);
    }
    for (int e=lane; e<100; e+=64){
      int i=e/10, j=e-10*i;
      M[e] = wv ? gen_disp_f(i,j,zr,zi) : gen_squeeze_f(i,j,zr,zi);
    }
  }
  __syncthreads();
  expm_f32(true, 10, M, P, T, R, lane);
  cxf* Rs = (cxf*)scr[0][3];
  cxf* Rd = (cxf*)scr[1][3];
  if (tid < 10) col[tid] = Rs[tid*10];           // squeeze column 0
  __syncthreads();
  if (tid < 10){
    float ax=0.f, ay=0.f;
    for (int k=0;k<10;k++){
      cxf d = Rd[tid*10+k], c = col[k];
      ax += d.x*c.x - d.y*c.y;
      ay += d.x*c.y + d.y*c.x;
    }
    uacc[tid] = {ax, ay};
  }
  __syncthreads();
  if (tid < 10){
    float rx, ry;
    if (w == 0){
      rx = 0.f; ry = 0.f;
      for (int k=0;k<10;k++){
        float v = wsf[k*10 + tid];               // (V^T)[tid][k]
        rx += v*uacc[k].x;
        ry += v*uacc[k].y;
      }
    } else { rx = uacc[tid].x; ry = uacc[tid].y; }
    float* u_out = wsf + U_OFF + (b*40 + w*10 + tid)*2;
    u_out[0] = rx;
    u_out[1] = ry;
  }
}

// ---------------- Kernel C: the circuit, state-only LDS (R9 verbatim) ------

#define DECL_ACCP \
  v2f a0={0.f,0.f}, a1={0.f,0.f}, a2={0.f,0.f}, a3={0.f,0.f}, a4={0.f,0.f}, \
      a5={0.f,0.f}, a6={0.f,0.f}, a7={0.f,0.f}, a8={0.f,0.f}, a9={0.f,0.f};

#define CKP(i) { v2f u = *(const v2f*)&U[kk+(i)]; \
  a##i = __builtin_elementwise_fma((v2f){u.x,u.x}, vv, a##i); \
  a##i = __builtin_elementwise_fma((v2f){-u.y,u.y}, vs, a##i); }
#define RKP(i) { float u = Mt[kk+(i)]; \
  a##i = __builtin_elementwise_fma((v2f){u,u}, vv, a##i); }
#define BKP(r) { v2f u = *(const v2f*)&Bt[kk+(r)]; \
  a##r = __builtin_elementwise_fma((v2f){u.x,u.x}, vv, a##r); \
  a##r = __builtin_elementwise_fma((v2f){-u.y,u.y}, vs, a##r); }

#define PSTORE(i) { *(v2f*)&S[base + (i)*sm] = a##i; }
#define PALLSTORE PSTORE(0) PSTORE(1) PSTORE(2) PSTORE(3) PSTORE(4) PSTORE(5) PSTORE(6) PSTORE(7) PSTORE(8) PSTORE(9)
#define BPSTORE(r) if ((r) < sz){ *(v2f*)&S[wadr] = a##r; wadr += ds; }
#define BPALLSTORE BPSTORE(0) BPSTORE(1) BPSTORE(2) BPSTORE(3) BPSTORE(4) BPSTORE(5) BPSTORE(6) BPSTORE(7) BPSTORE(8) BPSTORE(9)

__device__ __forceinline__ void apply1_c(cxf* S, const cxf* __restrict__ U, int m, int tid){
  const int sm = (m==0)?1000:((m==1)?100:((m==2)?10:1));
  const int r0 = (m==0)?1:0, r1=(m<=1)?2:1, r2=(m<=2)?3:2;
  const int s0 = (r0==0)?1000:((r0==1)?100:((r0==2)?10:1));
  const int s1 = (r1==0)?1000:((r1==1)?100:((r1==2)?10:1));
  const int s2 = (r2==0)?1000:((r2==1)?100:((r2==2)?10:1));
  int f = tid;
  if (f < 1000){
    int c0=f/100, rem=f-100*c0, c1=rem/10, c2=rem-10*c1;
    int base = c0*s0 + c1*s1 + c2*s2;
    DECL_ACCP
    #pragma unroll 2
    for (int k=0;k<10;k++){
      v2f vv = *(const v2f*)&S[base + k*sm];
      v2f vs = {vv.y, vv.x};
      int kk = k*10;
      CKP(0) CKP(1) CKP(2) CKP(3) CKP(4) CKP(5) CKP(6) CKP(7) CKP(8) CKP(9)
    }
    PALLSTORE
  }
}

__device__ __forceinline__ void apply1_r(cxf* S, const float* __restrict__ Mt, int m, int tid){
  const int sm = (m==0)?1000:((m==1)?100:((m==2)?10:1));
  const int r0 = (m==0)?1:0, r1=(m<=1)?2:1, r2=(m<=2)?3:2;
  const int s0 = (r0==0)?1000:((r0==1)?100:((r0==2)?10:1));
  const int s1 = (r1==0)?1000:((r1==1)?100:((r1==2)?10:1));
  const int s2 = (r2==0)?1000:((r2==1)?100:((r2==2)?10:1));
  int f = tid;
  if (f < 1000){
    int c0=f/100, rem=f-100*c0, c1=rem/10, c2=rem-10*c1;
    int base = c0*s0 + c1*s1 + c2*s2;
    DECL_ACCP
    #pragma unroll 2
    for (int k=0;k<10;k++){
      v2f vv = *(const v2f*)&S[base + k*sm];
      int kk = k*10;
      RKP(0) RKP(1) RKP(2) RKP(3) RKP(4) RKP(5) RKP(6) RKP(7) RKP(8) RKP(9)
    }
    PALLSTORE
  }
}

__device__ __forceinline__ void applyW(cxf* S, const float* __restrict__ Wall, int m1, int m2, int tid){
  const int sm  = (m2==0)?1000:((m2==1)?100:((m2==2)?10:1));
  const int sm1 = (m1==0)?1000:((m1==1)?100:((m1==2)?10:1));
  int ra=-1, rb=-1;
  for (int q=0;q<4;q++) if (q!=m1 && q!=m2){ if (ra<0) ra=q; else rb=q; }
  const int sa = (ra==0)?1000:((ra==1)?100:((ra==2)?10:1));
  const int sb = (rb==0)?1000:((rb==1)?100:((rb==2)?10:1));
  int f = tid;
  if (f < 1000){
    int n = f/100, rem = f-100*n, qa = rem/10, qb = rem-10*qa;
    int base = n*sm1 + qa*sa + qb*sb;
    const float* __restrict__ Mt = Wall + n*100;   // transposed W_n
    DECL_ACCP
    #pragma unroll 2
    for (int k=0;k<10;k++){
      v2f vv = *(const v2f*)&S[base + k*sm];
      int kk = k*10;
      RKP(0) RKP(1) RKP(2) RKP(3) RKP(4) RKP(5) RKP(6) RKP(7) RKP(8) RKP(9)
    }
    PALLSTORE
  }
}

__device__ __forceinline__ void applyBS(cxf* S, const cxf* __restrict__ BSp, int m1, int m2, int tid){
  int ra=-1, rb=-1;
  for (int q=0;q<4;q++) if (q!=m1 && q!=m2){ if (ra<0) ra=q; else rb=q; }
  const int sa = (ra==0)?1000:((ra==1)?100:((ra==2)?10:1));
  const int sb = (rb==0)?1000:((rb==1)?100:((rb==2)?10:1));
  const int s1 = (m1==0)?1000:((m1==1)?100:((m1==2)?10:1));
  const int s2 = (m2==0)?1000:((m2==1)?100:((m2==2)?10:1));
  const int ds = s1 - s2;
  #pragma unroll 1
  for (int w0=0; w0<2048; w0+=NTB){
    int it = w0 + tid;
    if (it < 1900){
      int bn = it/100, rest = it-100*bn;
      int ilo = bn<10?0:bn-9, ihi = bn<10?bn:9, sz = ihi-ilo+1;
      int ca = rest/10, cb = rest-10*ca;
      int base = ca*sa + cb*sb;
      const cxf* __restrict__ Bt = BSp + bn*100;   // transposed
      DECL_ACCP
      int radr = base + ilo*s1 + (bn-ilo)*s2;
      int kk = 0;
      #pragma unroll 1
      for (int c=0;c<sz;c++){
        v2f vv = *(const v2f*)&S[radr];
        v2f vs = {vv.y, vv.x};
        BKP(0) BKP(1) BKP(2) BKP(3) BKP(4) BKP(5) BKP(6) BKP(7) BKP(8) BKP(9)
        radr += ds; kk += 10;
      }
      int wadr = base + ilo*s1 + (bn-ilo)*s2;
      BPALLSTORE
    }
  }
}

__global__ __launch_bounds__(NTB)
__attribute__((amdgpu_waves_per_eu(8)))
void state_kernel(const float* __restrict__ wd, const float* __restrict__ bd,
                  const float* __restrict__ wsf, float* __restrict__ out){
  extern __shared__ __align__(16) char smem[];
  cxf* S    = (cxf*)smem;                 // 10000 cxf (80000 B)
  cxf* uv   = (cxf*)(smem + 80000);       // 4*10 encoding vectors
  float* red = (float*)(smem + 80320);    // 16

  const float* __restrict__ V   = wsf;            // for V^T gate
  const float* __restrict__ VT  = wsf + 100;      // for V gate
  const float* __restrict__ W   = wsf + 200;
  const cxf*   __restrict__ BSm = (const cxf*)(wsf + 1200);
  const cxf*   __restrict__ UL  = (const cxf*)(wsf + 5000);
  const cxf*   __restrict__ uw  = (const cxf*)(wsf + U_OFF);

  const int tid = threadIdx.x, wv = tid>>6, lane = tid&63;
  const int b = blockIdx.x;

  if (tid < 40) uv[tid] = uw[b*40 + tid];
  __syncthreads();

  // Init: product state S = u0 (x) u1 (x) u2 (x) u3  (V0^T folded in u0)
  for (int e=tid; e<10000; e+=NTB){
    int c0=e/1000, r_=e-1000*c0, c1=r_/100, r2_=r_-100*c1, c2=r2_/10, c3=r2_-10*c2;
    cxf A = uv[c0], B = uv[10+c1], C = uv[20+c2], D = uv[30+c3];
    float pr = A.x*B.x - A.y*B.y, pi = A.x*B.y + A.y*B.x;
    float qr = pr*C.x - pi*C.y,  qi = pr*C.y + pi*C.x;
    cxf o; o.x = qr*D.x - qi*D.y; o.y = qr*D.y + qi*D.x;
    S[e] = o;
  }
  __syncthreads();

  for (int L=0; L<2; ++L){
    // CX group a=0 (V0^T folded into u0 / UL[0]):
    applyW(S, W, 0, 1, tid); __syncthreads();
    applyW(S, W, 0, 2, tid); __syncthreads();
    applyW(S, W, 0, 3, tid); __syncthreads();
    apply1_r(S, VT, 0, tid); __syncthreads();      // V gate
    // a=1:
    apply1_r(S, V, 1, tid);  __syncthreads();      // V^T gate
    applyW(S, W, 1, 2, tid); __syncthreads();
    applyW(S, W, 1, 3, tid); __syncthreads();
    apply1_r(S, VT, 1, tid); __syncthreads();
    // a=2:
    apply1_r(S, V, 2, tid);  __syncthreads();
    applyW(S, W, 2, 3, tid); __syncthreads();
    apply1_r(S, VT, 2, tid); __syncthreads();
    // Beamsplitters:
    applyBS(S, BSm, 0, 1, tid); __syncthreads();
    applyBS(S, BSm, 1, 2, tid); __syncthreads();
    applyBS(S, BSm, 2, 3, tid); __syncthreads();
    applyBS(S, BSm, 3, 0, tid); __syncthreads();
    // Layer single-mode gates (UL[0] carries next layer's V0^T):
    for (int w=0; w<4; ++w){ apply1_c(S, UL + (L*4+w)*100, w, tid); __syncthreads(); }
  }

  float w0 = wd[0], w1 = wd[1], w2 = wd[2];
  float acc = 0.f;
  for (int e=tid; e<10000; e+=NTB){
    cxf z = S[e];
    float p = z.x*z.x + z.y*z.y;
    int n0 = e/1000, r_ = e-1000*n0, n1 = r_/100, r2_ = r_-100*n1, n2 = r2_/10;
    acc += p * ((float)n0*w0 + (float)n1*w1 + (float)n2*w2);
  }
  for (int off=32; off; off>>=1) acc += __shfl_down(acc, off, 64);
  if (lane == 0) red[wv] = acc;
  __syncthreads();
  if (tid == 0){
    float s = 0.f;
    for (int i=0;i<16;i++) s += red[i];
    out[b] = s + bd[0];
  }
}

} // anonymous namespace

extern "C" void kernel_launch(void* const* d_in, const int* in_sizes, int n_in,
                              void* d_out, int out_size, void* d_ws, size_t ws_size,
                              hipStream_t stream){
  const float* jets   = (const float*)d_in[0];
  const float* sscale = (const float*)d_in[1];
  const float* dmag   = (const float*)d_in[2];
  const float* dphase = (const float*)d_in[3];
  const float* smag   = (const float*)d_in[4];
  const float* sphase = (const float*)d_in[5];
  const float* wd     = (const float*)d_in[6];
  const float* bd     = (const float*)d_in[7];
  float* out = (float*)d_out;
  float* wsf = (float*)d_ws;
  int B = in_sizes[0] / 12;

  (void)hipFuncSetAttribute(reinterpret_cast<const void*>(&state_kernel),
                            hipFuncAttributeMaxDynamicSharedMemorySize, SMEM_BYTES);

  gates_kernel<<<12, 256, 0, stream>>>(dmag, dphase, smag, sphase, wsf);
  fuse_kernel<<<1, 512, 0, stream>>>(wsf);
  enc_kernel<<<B*4, 128, 0, stream>>>(jets, sscale, wsf);
  state_kernel<<<B, NTB, SMEM_BYTES, stream>>>(wd, bd, wsf, out);
}

// Round 13
// 1094.688 us; speedup vs baseline: 1.7403x; 1.0207x over previous
//
#include <hip/hip_runtime.h>
#include <math.h>

// CV-photonic circuit: WIRES=4, LAYERS=2, CUTOFF=10, BATCH=2048.
// R13 = R12 + algebraic pass fusion:
//  (1) L0's UL1/UL2/UL3 commute into L1's W(0,b): WU_b[n] = W_n*UL_b
//      (conditional COMPLEX gates) -> 3 fewer passes, -300 pk-fma/elem net.
//  (2) UL[L1,3] dropped (unitary on unmeasured axis 3 leaves marginals).
//  (3) Final UL0/1/2 fused with measurement: photons_m = sum_i i*|(UL_m v)_i|^2
//      -> 3 read-only measure passes, no stores, no final reduction pass.

namespace {

constexpr int NTB = 1024;                // threads per state block (16 waves)
constexpr int SMEM_BYTES = 80384;        // state 80000 + uv 320 + red 64
constexpr double THETA = 0.7853981633974483096; // pi/4

struct cxf { float x, y; };
typedef float v2f __attribute__((ext_vector_type(2)));

// ws float layout:
// [0,100)       V    (V[k*10+m]; used directly for the V^T gate)
// [100,200)     VT   (VT[k*10+i] = V[i][k]; used for the V gate)
// [200,1200)    Wt   (10 real 10x10, transposed: Wt[n*100+k*10+i]=W_n[i][k])
// [1200,5000)   BSt  cxf[19*100] zero-padded, transposed
// [5000,6600)   ULt  cxf[8*100]: f=0 (L0 UL0, VT-folded), f=4,5,6 (measure)
// [6600,9800)   stage cxf[16*100] raw S_lay (0..7) / D_lay (8..15)
// [9800,15800)  WUt  cxf[30*100]: WU_{b}[n] transposed, id=(b-1)*10+n
// [15872,...)   u    cxf[B*4*10] encoded per-(b,w) vectors
constexpr int U_OFF = 15872;

__device__ __forceinline__ cxf gen_squeeze_f(int i, int j, float zr, float zi){
  if (j == i+2){ float g = 0.5f*sqrtf((float)((i+1)*(i+2))); return {zr*g, -zi*g}; }
  if (i == j+2){ float g = 0.5f*sqrtf((float)((j+1)*(j+2))); return {-zr*g, -zi*g}; }
  return {0.f, 0.f};
}
__device__ __forceinline__ cxf gen_disp_f(int i, int j, float ar, float ai){
  if (i == j+1){ float g = sqrtf((float)i); return {ar*g, ai*g}; }
  if (j == i+1){ float g = sqrtf((float)j); return {-ar*g, ai*g}; }
  return {0.f, 0.f};
}

// Wave-cooperative fixed-schedule fp32 expm: result = exp(M), n x n (n<=10).
__device__ void expm_f32(bool act, int n, cxf* M, cxf* P, cxf* T, cxf* R, int lane){
  const int n2 = n*n;
  if (act){
    for (int e=lane; e<n2; e+=64){ M[e].x *= 0x1p-10f; M[e].y *= 0x1p-10f; }
    for (int e=lane; e<n2; e+=64){
      P[e] = M[e];
      cxf r = M[e];
      if (e % (n+1) == 0) r.x += 1.f;
      R[e] = r;
    }
  }
  __syncthreads();
  for (int t=2; t<=12; ++t){
    if (act){
      float inv = 1.f/(float)t;
      for (int e=lane; e<n2; e+=64){
        int i = e/n, j = e - i*n;
        float ax=0.f, ay=0.f;
        for (int k=0;k<n;k++){
          cxf p = P[i*n+k], m = M[k*n+j];
          ax += p.x*m.x - p.y*m.y;
          ay += p.x*m.y + p.y*m.x;
        }
        T[e] = {ax*inv, ay*inv};
      }
    }
    __syncthreads();
    { cxf* tmp = P; P = T; T = tmp; }
    if (act){ for (int e=lane; e<n2; e+=64){ R[e].x += P[e].x; R[e].y += P[e].y; } }
    __syncthreads();
  }
  for (int s=0; s<10; ++s){
    if (act){
      for (int e=lane; e<n2; e+=64){
        int i = e/n, j = e - i*n;
        float ax=0.f, ay=0.f;
        for (int k=0;k<n;k++){
          cxf p = R[i*n+k], q = R[k*n+j];
          ax += p.x*q.x - p.y*q.y;
          ay += p.x*q.y + p.y*q.x;
        }
        T[e] = {ax, ay};
      }
    }
    __syncthreads();
    { cxf* tmp = R; R = T; T = tmp; }
    __syncthreads();
  }
}

// ------------- Kernel A: 45 expm tasks fully parallel over 12 blocks -------
__global__ __launch_bounds__(256)
void gates_kernel(const float* __restrict__ dmag, const float* __restrict__ dphase,
                  const float* __restrict__ smag, const float* __restrict__ sphase,
                  float* __restrict__ wsf){
  __shared__ double lam[10];
  __shared__ float scr[4][4][200];      // [wave][buf] cxf[100]
  const int tid = threadIdx.x;
  const int wv = tid >> 6, lane = tid & 63, g = blockIdx.x;
  float* ws_V  = wsf;
  float* ws_VT = wsf + 100;
  float* ws_W  = wsf + 200;
  cxf* ws_BS   = (cxf*)(wsf + 1200);
  cxf* ws_stage= (cxf*)(wsf + 6600);

  if (tid < 10){
    double lo = -6.0, hi = 6.0;
    for (int it=0; it<80; ++it){
      double mid = 0.5*(lo+hi);
      int cnt = 0; double q = 1.0;
      for (int i=0;i<10;i++){
        q = -mid - (i ? (double)i/q : 0.0);
        if (fabs(q) < 1e-300) q = -1e-300;
        if (q < 0.0) cnt++;
      }
      if (cnt > tid) hi = mid; else lo = mid;
    }
    double x = 0.5*(lo+hi);
    double p[10];
    p[0] = 1.0; p[1] = x;
    for (int k=1;k<9;k++) p[k+1] = (x*p[k] - sqrt((double)k)*p[k-1]) * (1.0/sqrt((double)(k+1)));
    double nn=0.0; for (int k=0;k<10;k++) nn += p[k]*p[k];
    double inv = 1.0/sqrt(nn);
    lam[tid] = x;
    if (g == 0){
      for (int k=0;k<10;k++){
        float v = (float)(p[k]*inv);
        ws_V[k*10+tid]  = v;
        ws_VT[tid*10+k] = v;
      }
    }
  }
  __syncthreads();

  int t = g*4 + wv;
  bool act = (t < 45);
  int n = 10, bn = 0, ilo = 0;
  if (act && t >= 10 && t < 29){
    bn = t - 10; ilo = bn < 10 ? 0 : bn - 9;
    int ihi = bn < 10 ? bn : 9;
    n = ihi - ilo + 1;
  }
  cxf* M = (cxf*)scr[wv][0];
  cxf* P = (cxf*)scr[wv][1];
  cxf* T = (cxf*)scr[wv][2];
  cxf* R = (cxf*)scr[wv][3];
  if (act){
    if (t < 10){
      float l = (float)lam[t];   // Q = -0.5*(a - ad)
      for (int e=lane; e<100; e+=64){
        int i=e/10, j=e-10*i;
        float v = 0.f;
        if (j == i+1) v = -0.5f*l*sqrtf((float)(i+1));
        else if (i == j+1) v = 0.5f*l*sqrtf((float)i);
        M[e] = {v, 0.f};
      }
    } else if (t < 29){
      for (int e=lane; e<n*n; e+=64){
        int rr=e/n, c=e-n*rr;
        float v = 0.f;
        if (c == rr+1) v = (float)THETA*sqrtf((float)((ilo+rr+1)*(bn-ilo-rr)));
        else if (rr == c+1) v = (float)THETA*sqrtf((float)((ilo+c+1)*(bn-ilo-c)));
        M[e] = {0.f, v};
      }
    } else {
      int idx = t-29, kind = idx>>3, L=(idx>>2)&1, w=idx&3;
      float r_ = kind ? dmag[L*4+w]   : smag[L*4+w];
      float ph = kind ? dphase[L*4+w] : sphase[L*4+w];
      float zr = r_*cosf(ph), zi = r_*sinf(ph);
      for (int e=lane; e<100; e+=64){
        int i=e/10, j=e-10*i;
        M[e] = kind ? gen_disp_f(i,j,zr,zi) : gen_squeeze_f(i,j,zr,zi);
      }
    }
  }
  __syncthreads();
  expm_f32(act, n, M, P, T, R, lane);
  if (act){
    if (t < 10){
      for (int e=lane;e<100;e+=64){
        int i=e/10, j=e-10*i;
        ws_W[t*100 + j*10 + i] = R[e].x;   // transposed, real
      }
    } else if (t < 29){
      for (int e=lane;e<100;e+=64){
        int rr=e/10, c=e-10*rr;
        cxf o; o.x=0.f; o.y=0.f;
        if (rr < n && c < n) o = R[rr*n+c];
        ws_BS[bn*100 + c*10 + rr] = o;     // zero-padded + transposed
      }
    } else {
      int idx = t-29;
      for (int e=lane;e<100;e+=64) ws_stage[idx*100 + e] = R[e];
    }
  }
}

// ---- Kernel A2: UL products, VT fold, and WU_b[n] = W_n * UL_b fusion -----
__global__ __launch_bounds__(512)
void fuse_kernel(float* __restrict__ wsf){
  __shared__ cxf ulraw[8][100];          // raw UL[f] = D*S, [i*10+j]
  const int tid = threadIdx.x, wv = tid>>6, lane = tid&63;
  const cxf* stage = (const cxf*)(wsf + 6600);
  cxf* ws_UL = (cxf*)(wsf + 5000);
  cxf* ws_WU = (cxf*)(wsf + 9800);
  const float* V  = wsf;
  const float* Wt = wsf + 200;
  const cxf* Sm = stage + wv*100;
  const cxf* Dm = stage + (8+wv)*100;
  for (int e=lane; e<100; e+=64){
    int i=e/10, j=e-10*i;
    float ax=0.f, ay=0.f;
    for (int k=0;k<10;k++){
      cxf d=Dm[i*10+k], s=Sm[k*10+j];
      ax += d.x*s.x - d.y*s.y;
      ay += d.x*s.y + d.y*s.x;
    }
    ulraw[wv][e] = {ax, ay};
  }
  __syncthreads();
  // f=0 only: UL0 <- V^T * UL0 (carries L1's V0^T). Two elems per lane.
  cxf t0={0.f,0.f}, t1={0.f,0.f};
  if (wv == 0){
    {
      int e=lane, i=e/10, j=e-10*i;
      float ox=0.f, oy=0.f;
      for (int k=0;k<10;k++){ float v=V[k*10+i]; ox+=v*ulraw[0][k*10+j].x; oy+=v*ulraw[0][k*10+j].y; }
      t0 = {ox, oy};
    }
    if (lane+64 < 100){
      int e=lane+64, i=e/10, j=e-10*i;
      float ox=0.f, oy=0.f;
      for (int k=0;k<10;k++){ float v=V[k*10+i]; ox+=v*ulraw[0][k*10+j].x; oy+=v*ulraw[0][k*10+j].y; }
      t1 = {ox, oy};
    }
  }
  __syncthreads();
  if (wv == 0){
    ulraw[0][lane] = t0;
    if (lane+64 < 100) ulraw[0][lane+64] = t1;
  }
  __syncthreads();
  // Export ULt (transposed) for f in {0,4,5,6}
  for (int e=tid; e<400; e+=512){
    int fi = e/100, r = e-100*fi;
    int f = (fi==0) ? 0 : (3+fi);        // 0,4,5,6
    int i=r/10, j=r-10*i;
    ws_UL[f*100 + j*10 + i] = ulraw[f][i*10+j];
  }
  // Phase 2: WU_b[n] = W_n * ulraw[b], id=(b-1)*10+n, 30 tasks over 8 waves.
  for (int round=0; round<4; ++round){
    int id = round*8 + wv;
    if (id < 30){
      int b = 1 + id/10, n = id - (id/10)*10;
      const cxf* Ub = ulraw[b];
      for (int e=lane; e<100; e+=64){
        int i=e/10, j=e-10*i;
        float ax=0.f, ay=0.f;
        for (int k=0;k<10;k++){
          float w = Wt[n*100 + k*10 + i];   // W_n[i][k]
          ax += w*Ub[k*10+j].x;
          ay += w*Ub[k*10+j].y;
        }
        cxf o; o.x=ax; o.y=ay;
        ws_WU[id*100 + j*10 + i] = o;       // transposed
      }
    }
  }
}

// ------------- Kernel B: per-(b,w) encoding vector u = D*(S*e0), fp32 ------
__global__ __launch_bounds__(128)
void enc_kernel(const float* __restrict__ jets, const float* __restrict__ sscale,
                float* __restrict__ wsf){
  __shared__ float scr[2][4][200];
  __shared__ cxf col[10];
  __shared__ cxf uacc[10];
  const int tid = threadIdx.x, wv = tid>>6, lane = tid&63;
  const int blk = blockIdx.x, b = blk>>2, w = blk&3;

  float eta = jets[b*12 + w*3 + 0];
  float jph = jets[b*12 + w*3 + 1];
  float pt  = jets[b*12 + w*3 + 2];

  cxf* M = (cxf*)scr[wv][0];
  cxf* P = (cxf*)scr[wv][1];
  cxf* T = (cxf*)scr[wv][2];
  cxf* R = (cxf*)scr[wv][3];
  {
    float zr, zi;
    if (wv == 0){ float phs = pt*jph*0.5f; zr = eta*cosf(phs); zi = eta*sinf(phs); }
    else {
      double sc = 10.0/(1.0 + exp(-(double)sscale[0])) + 0.01;
      float mag = (float)sc*pt; zr = mag*cosf(eta); zi = mag*sinf(eta);
    }
    for (int e=lane; e<100; e+=64){
      int i=e/10, j=e-10*i;
      M[e] = wv ? gen_disp_f(i,j,zr,zi) : gen_squeeze_f(i,j,zr,zi);
    }
  }
  __syncthreads();
  expm_f32(true, 10, M, P, T, R, lane);
  cxf* Rs = (cxf*)scr[0][3];
  cxf* Rd = (cxf*)scr[1][3];
  if (tid < 10) col[tid] = Rs[tid*10];           // squeeze column 0
  __syncthreads();
  if (tid < 10){
    float ax=0.f, ay=0.f;
    for (int k=0;k<10;k++){
      cxf d = Rd[tid*10+k], c = col[k];
      ax += d.x*c.x - d.y*c.y;
      ay += d.x*c.y + d.y*c.x;
    }
    uacc[tid] = {ax, ay};
  }
  __syncthreads();
  if (tid < 10){
    float rx, ry;
    if (w == 0){
      rx = 0.f; ry = 0.f;
      for (int k=0;k<10;k++){
        float v = wsf[k*10 + tid];               // (V^T)[tid][k]
        rx += v*uacc[k].x;
        ry += v*uacc[k].y;
      }
    } else { rx = uacc[tid].x; ry = uacc[tid].y; }
    float* u_out = wsf + U_OFF + (b*40 + w*10 + tid)*2;
    u_out[0] = rx;
    u_out[1] = ry;
  }
}

// ---------------- Kernel C: the circuit, state-only LDS --------------------

#define DECL_ACCP \
  v2f a0={0.f,0.f}, a1={0.f,0.f}, a2={0.f,0.f}, a3={0.f,0.f}, a4={0.f,0.f}, \
      a5={0.f,0.f}, a6={0.f,0.f}, a7={0.f,0.f}, a8={0.f,0.f}, a9={0.f,0.f};

#define CKP(i) { v2f u = *(const v2f*)&U[kk+(i)]; \
  a##i = __builtin_elementwise_fma((v2f){u.x,u.x}, vv, a##i); \
  a##i = __builtin_elementwise_fma((v2f){-u.y,u.y}, vs, a##i); }
#define RKP(i) { float u = Mt[kk+(i)]; \
  a##i = __builtin_elementwise_fma((v2f){u,u}, vv, a##i); }
#define BKP(r) { v2f u = *(const v2f*)&Bt[kk+(r)]; \
  a##r = __builtin_elementwise_fma((v2f){u.x,u.x}, vv, a##r); \
  a##r = __builtin_elementwise_fma((v2f){-u.y,u.y}, vs, a##r); }

#define PSTORE(i) { *(v2f*)&S[base + (i)*sm] = a##i; }
#define PALLSTORE PSTORE(0) PSTORE(1) PSTORE(2) PSTORE(3) PSTORE(4) PSTORE(5) PSTORE(6) PSTORE(7) PSTORE(8) PSTORE(9)
#define BPSTORE(r) if ((r) < sz){ *(v2f*)&S[wadr] = a##r; wadr += ds; }
#define BPALLSTORE BPSTORE(0) BPSTORE(1) BPSTORE(2) BPSTORE(3) BPSTORE(4) BPSTORE(5) BPSTORE(6) BPSTORE(7) BPSTORE(8) BPSTORE(9)

__device__ __forceinline__ void apply1_c(cxf* S, const cxf* __restrict__ U, int m, int tid){
  const int sm = (m==0)?1000:((m==1)?100:((m==2)?10:1));
  const int r0 = (m==0)?1:0, r1=(m<=1)?2:1, r2=(m<=2)?3:2;
  const int s0 = (r0==0)?1000:((r0==1)?100:((r0==2)?10:1));
  const int s1 = (r1==0)?1000:((r1==1)?100:((r1==2)?10:1));
  const int s2 = (r2==0)?1000:((r2==1)?100:((r2==2)?10:1));
  int f = tid;
  if (f < 1000){
    int c0=f/100, rem=f-100*c0, c1=rem/10, c2=rem-10*c1;
    int base = c0*s0 + c1*s1 + c2*s2;
    DECL_ACCP
    #pragma unroll 2
    for (int k=0;k<10;k++){
      v2f vv = *(const v2f*)&S[base + k*sm];
      v2f vs = {vv.y, vv.x};
      int kk = k*10;
      CKP(0) CKP(1) CKP(2) CKP(3) CKP(4) CKP(5) CKP(6) CKP(7) CKP(8) CKP(9)
    }
    PALLSTORE
  }
}

__device__ __forceinline__ void apply1_r(cxf* S, const float* __restrict__ Mt, int m, int tid){
  const int sm = (m==0)?1000:((m==1)?100:((m==2)?10:1));
  const int r0 = (m==0)?1:0, r1=(m<=1)?2:1, r2=(m<=2)?3:2;
  const int s0 = (r0==0)?1000:((r0==1)?100:((r0==2)?10:1));
  const int s1 = (r1==0)?1000:((r1==1)?100:((r1==2)?10:1));
  const int s2 = (r2==0)?1000:((r2==1)?100:((r2==2)?10:1));
  int f = tid;
  if (f < 1000){
    int c0=f/100, rem=f-100*c0, c1=rem/10, c2=rem-10*c1;
    int base = c0*s0 + c1*s1 + c2*s2;
    DECL_ACCP
    #pragma unroll 2
    for (int k=0;k<10;k++){
      v2f vv = *(const v2f*)&S[base + k*sm];
      int kk = k*10;
      RKP(0) RKP(1) RKP(2) RKP(3) RKP(4) RKP(5) RKP(6) RKP(7) RKP(8) RKP(9)
    }
    PALLSTORE
  }
}

__device__ __forceinline__ void applyW(cxf* S, const float* __restrict__ Wall, int m1, int m2, int tid){
  const int sm  = (m2==0)?1000:((m2==1)?100:((m2==2)?10:1));
  const int sm1 = (m1==0)?1000:((m1==1)?100:((m1==2)?10:1));
  int ra=-1, rb=-1;
  for (int q=0;q<4;q++) if (q!=m1 && q!=m2){ if (ra<0) ra=q; else rb=q; }
  const int sa = (ra==0)?1000:((ra==1)?100:((ra==2)?10:1));
  const int sb = (rb==0)?1000:((rb==1)?100:((rb==2)?10:1));
  int f = tid;
  if (f < 1000){
    int n = f/100, rem = f-100*n, qa = rem/10, qb = rem-10*qa;
    int base = n*sm1 + qa*sa + qb*sb;
    const float* __restrict__ Mt = Wall + n*100;   // transposed W_n
    DECL_ACCP
    #pragma unroll 2
    for (int k=0;k<10;k++){
      v2f vv = *(const v2f*)&S[base + k*sm];
      int kk = k*10;
      RKP(0) RKP(1) RKP(2) RKP(3) RKP(4) RKP(5) RKP(6) RKP(7) RKP(8) RKP(9)
    }
    PALLSTORE
  }
}

// Conditional COMPLEX gate on m2, selected by c0 (m1=0): WU_b[n] = W_n*UL_b.
__device__ __forceinline__ void applyWU(cxf* S, const cxf* __restrict__ WUall, int m2, int tid){
  const int sm = (m2==1)?100:((m2==2)?10:1);
  const int ra = (m2==1)?2:1;
  const int rb = (m2==3)?2:3;
  const int sa = (ra==1)?100:10;
  const int sb = (rb==2)?10:1;
  int f = tid;
  if (f < 1000){
    int n = f/100, rem = f-100*n, qa = rem/10, qb = rem-10*qa;
    int base = n*1000 + qa*sa + qb*sb;
    const cxf* __restrict__ U = WUall + n*100;     // transposed complex
    DECL_ACCP
    #pragma unroll 2
    for (int k=0;k<10;k++){
      v2f vv = *(const v2f*)&S[base + k*sm];
      v2f vs = {vv.y, vv.x};
      int kk = k*10;
      CKP(0) CKP(1) CKP(2) CKP(3) CKP(4) CKP(5) CKP(6) CKP(7) CKP(8) CKP(9)
    }
    PALLSTORE
  }
}

// Read-only measure pass: returns sum_i i*|(U v)_i|^2 over this thread's fiber.
__device__ __forceinline__ float measure1(const cxf* S, const cxf* __restrict__ U, int m, int tid){
  const int sm = (m==0)?1000:((m==1)?100:10);
  const int r0 = (m==0)?1:0, r1=(m<=1)?2:1, r2=3;
  const int s0 = (r0==0)?1000:100;
  const int s1 = (r1==1)?100:10;
  const int s2 = 1;
  int f = tid;
  float s = 0.f;
  if (f < 1000){
    int c0=f/100, rem=f-100*c0, c1=rem/10, c2=rem-10*c1;
    int base = c0*s0 + c1*s1 + c2*s2;
    DECL_ACCP
    #pragma unroll 2
    for (int k=0;k<10;k++){
      v2f vv = *(const v2f*)&S[base + k*sm];
      v2f vs = {vv.y, vv.x};
      int kk = k*10;
      CKP(0) CKP(1) CKP(2) CKP(3) CKP(4) CKP(5) CKP(6) CKP(7) CKP(8) CKP(9)
    }
    float p;
    p = a1.x*a1.x + a1.y*a1.y; s += 1.f*p;
    p = a2.x*a2.x + a2.y*a2.y; s += 2.f*p;
    p = a3.x*a3.x + a3.y*a3.y; s += 3.f*p;
    p = a4.x*a4.x + a4.y*a4.y; s += 4.f*p;
    p = a5.x*a5.x + a5.y*a5.y; s += 5.f*p;
    p = a6.x*a6.x + a6.y*a6.y; s += 6.f*p;
    p = a7.x*a7.x + a7.y*a7.y; s += 7.f*p;
    p = a8.x*a8.x + a8.y*a8.y; s += 8.f*p;
    p = a9.x*a9.x + a9.y*a9.y; s += 9.f*p;
  }
  return s;
}

__device__ __forceinline__ void applyBS(cxf* S, const cxf* __restrict__ BSp, int m1, int m2, int tid){
  int ra=-1, rb=-1;
  for (int q=0;q<4;q++) if (q!=m1 && q!=m2){ if (ra<0) ra=q; else rb=q; }
  const int sa = (ra==0)?1000:((ra==1)?100:((ra==2)?10:1));
  const int sb = (rb==0)?1000:((rb==1)?100:((rb==2)?10:1));
  const int s1 = (m1==0)?1000:((m1==1)?100:((m1==2)?10:1));
  const int s2 = (m2==0)?1000:((m2==1)?100:((m2==2)?10:1));
  const int ds = s1 - s2;
  #pragma unroll 1
  for (int w0=0; w0<2048; w0+=NTB){
    int it = w0 + tid;
    if (it < 1900){
      int bn = it/100, rest = it-100*bn;
      int ilo = bn<10?0:bn-9, ihi = bn<10?bn:9, sz = ihi-ilo+1;
      int ca = rest/10, cb = rest-10*ca;
      int base = ca*sa + cb*sb;
      const cxf* __restrict__ Bt = BSp + bn*100;   // transposed
      DECL_ACCP
      int radr = base + ilo*s1 + (bn-ilo)*s2;
      int kk = 0;
      #pragma unroll 1
      for (int c=0;c<sz;c++){
        v2f vv = *(const v2f*)&S[radr];
        v2f vs = {vv.y, vv.x};
        BKP(0) BKP(1) BKP(2) BKP(3) BKP(4) BKP(5) BKP(6) BKP(7) BKP(8) BKP(9)
        radr += ds; kk += 10;
      }
      int wadr = base + ilo*s1 + (bn-ilo)*s2;
      BPALLSTORE
    }
  }
}

__global__ __launch_bounds__(NTB)
__attribute__((amdgpu_waves_per_eu(8)))
void state_kernel(const float* __restrict__ wd, const float* __restrict__ bd,
                  const float* __restrict__ wsf, float* __restrict__ out){
  extern __shared__ __align__(16) char smem[];
  cxf* S    = (cxf*)smem;                 // 10000 cxf (80000 B)
  cxf* uv   = (cxf*)(smem + 80000);       // 4*10 encoding vectors
  float* red = (float*)(smem + 80320);    // 16

  const float* __restrict__ V   = wsf;            // for V^T gate
  const float* __restrict__ VT  = wsf + 100;      // for V gate
  const float* __restrict__ W   = wsf + 200;
  const cxf*   __restrict__ BSm = (const cxf*)(wsf + 1200);
  const cxf*   __restrict__ UL  = (const cxf*)(wsf + 5000);
  const cxf*   __restrict__ WU  = (const cxf*)(wsf + 9800);
  const cxf*   __restrict__ uw  = (const cxf*)(wsf + U_OFF);

  const int tid = threadIdx.x, wv = tid>>6, lane = tid&63;
  const int b = blockIdx.x;

  if (tid < 40) uv[tid] = uw[b*40 + tid];
  __syncthreads();

  // Init: product state S = u0 (x) u1 (x) u2 (x) u3  (L0's V0^T folded in u0)
  for (int e=tid; e<10000; e+=NTB){
    int c0=e/1000, r_=e-1000*c0, c1=r_/100, r2_=r_-100*c1, c2=r2_/10, c3=r2_-10*c2;
    cxf A = uv[c0], B = uv[10+c1], C = uv[20+c2], D = uv[30+c3];
    float pr = A.x*B.x - A.y*B.y, pi = A.x*B.y + A.y*B.x;
    float qr = pr*C.x - pi*C.y,  qi = pr*C.y + pi*C.x;
    cxf o; o.x = qr*D.x - qi*D.y; o.y = qr*D.y + qi*D.x;
    S[e] = o;
  }
  __syncthreads();

  // ---------------- Layer 0 ----------------
  applyW(S, W, 0, 1, tid); __syncthreads();
  applyW(S, W, 0, 2, tid); __syncthreads();
  applyW(S, W, 0, 3, tid); __syncthreads();
  apply1_r(S, VT, 0, tid); __syncthreads();      // V0
  apply1_r(S, V, 1, tid);  __syncthreads();      // V1^T
  applyW(S, W, 1, 2, tid); __syncthreads();
  applyW(S, W, 1, 3, tid); __syncthreads();
  apply1_r(S, VT, 1, tid); __syncthreads();      // V1
  apply1_r(S, V, 2, tid);  __syncthreads();      // V2^T
  applyW(S, W, 2, 3, tid); __syncthreads();
  apply1_r(S, VT, 2, tid); __syncthreads();      // V2
  applyBS(S, BSm, 0, 1, tid); __syncthreads();
  applyBS(S, BSm, 1, 2, tid); __syncthreads();
  applyBS(S, BSm, 2, 3, tid); __syncthreads();
  applyBS(S, BSm, 3, 0, tid); __syncthreads();
  apply1_c(S, UL, 0, tid); __syncthreads();      // UL0_L0 (carries L1's V0^T)

  // ---------------- Layer 1 ----------------
  // W(0,b) fused with L0's UL_b (conditional complex):
  applyWU(S, WU,        1, tid); __syncthreads();
  applyWU(S, WU + 1000, 2, tid); __syncthreads();
  applyWU(S, WU + 2000, 3, tid); __syncthreads();
  apply1_r(S, VT, 0, tid); __syncthreads();      // V0
  apply1_r(S, V, 1, tid);  __syncthreads();      // V1^T
  applyW(S, W, 1, 2, tid); __syncthreads();
  applyW(S, W, 1, 3, tid); __syncthreads();
  apply1_r(S, VT, 1, tid); __syncthreads();      // V1
  apply1_r(S, V, 2, tid);  __syncthreads();      // V2^T
  applyW(S, W, 2, 3, tid); __syncthreads();
  apply1_r(S, VT, 2, tid); __syncthreads();      // V2
  applyBS(S, BSm, 0, 1, tid); __syncthreads();
  applyBS(S, BSm, 1, 2, tid); __syncthreads();
  applyBS(S, BSm, 2, 3, tid); __syncthreads();
  applyBS(S, BSm, 3, 0, tid); __syncthreads();

  // Fused measurement: UL[L1,m] applied read-only; UL[L1,3] dropped (unitary
  // on unmeasured axis). No barriers needed between read-only passes.
  float w0 = wd[0], w1 = wd[1], w2 = wd[2];
  float acc = 0.f;
  acc += w0 * measure1(S, UL + 400, 0, tid);
  acc += w1 * measure1(S, UL + 500, 1, tid);
  acc += w2 * measure1(S, UL + 600, 2, tid);

  for (int off=32; off; off>>=1) acc += __shfl_down(acc, off, 64);
  if (lane == 0) red[wv] = acc;
  __syncthreads();
  if (tid == 0){
    float s = 0.f;
    for (int i=0;i<16;i++) s += red[i];
    out[b] = s + bd[0];
  }
}

} // anonymous namespace

extern "C" void kernel_launch(void* const* d_in, const int* in_sizes, int n_in,
                              void* d_out, int out_size, void* d_ws, size_t ws_size,
                              hipStream_t stream){
  const float* jets   = (const float*)d_in[0];
  const float* sscale = (const float*)d_in[1];
  const float* dmag   = (const float*)d_in[2];
  const float* dphase = (const float*)d_in[3];
  const float* smag   = (const float*)d_in[4];
  const float* sphase = (const float*)d_in[5];
  const float* wd     = (const float*)d_in[6];
  const float* bd     = (const float*)d_in[7];
  float* out = (float*)d_out;
  float* wsf = (float*)d_ws;
  int B = in_sizes[0] / 12;

  (void)hipFuncSetAttribute(reinterpret_cast<const void*>(&state_kernel),
                            hipFuncAttributeMaxDynamicSharedMemorySize, SMEM_BYTES);

  gates_kernel<<<12, 256, 0, stream>>>(dmag, dphase, smag, sphase, wsf);
  fuse_kernel<<<1, 512, 0, stream>>>(wsf);
  enc_kernel<<<B*4, 128, 0, stream>>>(jets, sscale, wsf);
  state_kernel<<<B, NTB, SMEM_BYTES, stream>>>(wd, bd, wsf, out);
}